// Round 1
// baseline (4620.382 us; speedup 1.0000x reference)
//
#include <hip/hip_runtime.h>

#define T_STEPS 2048
#define HID 64
#define GATES 256

__device__ __forceinline__ float sigmoid_f(float x) {
    float e = __expf(-x);                    // v_exp_f32 path; saturates correctly at +-inf
    return __fdividef(1.0f, 1.0f + e);
}

__device__ __forceinline__ float tanh_f(float x) {
    float xc = fminf(fmaxf(x, -15.0f), 15.0f);
    float e = __expf(2.0f * xc);             // e in [e^-30, e^30], no overflow
    return __fdividef(e - 1.0f, e + 1.0f);
}

// One block per batch element. 256 threads: thread g computes gate g (i,f,g,o x 64).
// Weights live in registers (~200 VGPR/thread). h0/h1 broadcast via LDS.
// c0/c1 kept redundantly in registers of every wave (deterministic).
__global__ __launch_bounds__(256, 2) void lstm2_fused(
    const float* __restrict__ x,
    const float* __restrict__ wih0, const float* __restrict__ whh0,
    const float* __restrict__ bih0, const float* __restrict__ bhh0,
    const float* __restrict__ wih1, const float* __restrict__ whh1,
    const float* __restrict__ bih1, const float* __restrict__ bhh1,
    float* __restrict__ out, int B)
{
    __shared__ float4 s_x[T_STEPS];      // 32 KB: whole input row x[b]
    __shared__ float4 s_h0[HID / 4];     // layer0 hidden state
    __shared__ float4 s_h1[HID / 4];     // layer1 hidden state
    __shared__ float  s_g0[GATES];       // layer0 pre-activation gates
    __shared__ float  s_g1[GATES];       // layer1 pre-activation gates

    const int tid = threadIdx.x;
    const int k  = tid & 63;            // hidden unit
    const int wv = tid >> 6;            // gate type (0=i,1=f,2=g,3=o)
    const int g  = tid;                 // gate row index
    const int b  = blockIdx.x;

    // ---- stage x[b] into LDS (2048 float4 = 32 KB, coalesced) ----
    const float4* xb = (const float4*)(x + (size_t)b * (T_STEPS * 4));
    for (int i = tid; i < T_STEPS; i += 256) s_x[i] = xb[i];
    if (tid < HID / 4)           s_h0[tid]           = make_float4(0.f, 0.f, 0.f, 0.f);
    else if (tid < HID / 2)      s_h1[tid - HID / 4] = make_float4(0.f, 0.f, 0.f, 0.f);

    // ---- load this thread's weight rows into registers ----
    float4 wi0 = ((const float4*)wih0)[g];   // w_ih_l0 row g: 4 floats
    float4 wh0[16], wi1[16], wh1[16];
    #pragma unroll
    for (int jj = 0; jj < 16; ++jj) {
        wh0[jj] = ((const float4*)whh0)[g * 16 + jj];
        wi1[jj] = ((const float4*)wih1)[g * 16 + jj];
        wh1[jj] = ((const float4*)whh1)[g * 16 + jj];
    }
    const float bias0 = bih0[g] + bhh0[g];
    const float bias1 = bih1[g] + bhh1[g];

    float c0 = 0.f, c1 = 0.f, h0cur = 0.f, h1cur = 0.f;
    float* op = out + (size_t)b * T_STEPS * HID + k;   // out1[b, t, k]

    __syncthreads();

    for (int t = 0; t < T_STEPS; ++t) {
        // ---------- Phase A: layer0 gates ----------
        float4 xt = s_x[t];
        float a0 = fmaf(wi0.x, xt.x, bias0);
        a0 = fmaf(wi0.y, xt.y, a0);
        a0 = fmaf(wi0.z, xt.z, a0);
        a0 = fmaf(wi0.w, xt.w, a0);
        float a1 = 0.f;
        #pragma unroll
        for (int jj = 0; jj < 16; jj += 2) {
            float4 h = s_h0[jj];
            a0 = fmaf(wh0[jj].x, h.x, a0);
            a0 = fmaf(wh0[jj].y, h.y, a0);
            a0 = fmaf(wh0[jj].z, h.z, a0);
            a0 = fmaf(wh0[jj].w, h.w, a0);
            float4 h2 = s_h0[jj + 1];
            a1 = fmaf(wh0[jj + 1].x, h2.x, a1);
            a1 = fmaf(wh0[jj + 1].y, h2.y, a1);
            a1 = fmaf(wh0[jj + 1].z, h2.z, a1);
            a1 = fmaf(wh0[jj + 1].w, h2.w, a1);
        }
        s_g0[g] = a0 + a1;
        __syncthreads();   // (1) gates0 visible; s_h0 reads done

        // ---------- Phase B: layer0 activations (all waves, redundant) ----------
        {
            float gi = sigmoid_f(s_g0[k]);
            float gf = sigmoid_f(s_g0[64 + k]);
            float gg = tanh_f   (s_g0[128 + k]);
            float go = sigmoid_f(s_g0[192 + k]);
            c0 = fmaf(gf, c0, gi * gg);
            h0cur = go * tanh_f(c0);
        }
        if (wv == 0) ((float*)s_h0)[k] = h0cur;
        __syncthreads();   // (2) new h0 visible

        // ---------- Phase C: layer1 gates ----------
        float q0 = bias1, q1 = 0.f, q2 = 0.f, q3 = 0.f;
        #pragma unroll
        for (int jj = 0; jj < 16; ++jj) {
            float4 hv = s_h0[jj];
            float4 gv = s_h1[jj];
            if (jj & 1) {
                q2 = fmaf(wi1[jj].x, hv.x, q2);
                q2 = fmaf(wi1[jj].y, hv.y, q2);
                q2 = fmaf(wi1[jj].z, hv.z, q2);
                q2 = fmaf(wi1[jj].w, hv.w, q2);
                q3 = fmaf(wh1[jj].x, gv.x, q3);
                q3 = fmaf(wh1[jj].y, gv.y, q3);
                q3 = fmaf(wh1[jj].z, gv.z, q3);
                q3 = fmaf(wh1[jj].w, gv.w, q3);
            } else {
                q0 = fmaf(wi1[jj].x, hv.x, q0);
                q0 = fmaf(wi1[jj].y, hv.y, q0);
                q0 = fmaf(wi1[jj].z, hv.z, q0);
                q0 = fmaf(wi1[jj].w, hv.w, q0);
                q1 = fmaf(wh1[jj].x, gv.x, q1);
                q1 = fmaf(wh1[jj].y, gv.y, q1);
                q1 = fmaf(wh1[jj].z, gv.z, q1);
                q1 = fmaf(wh1[jj].w, gv.w, q1);
            }
        }
        s_g1[g] = (q0 + q1) + (q2 + q3);
        __syncthreads();   // (3) gates1 visible; s_h1 reads done

        // ---------- Phase D: layer1 activations ----------
        {
            float gi = sigmoid_f(s_g1[k]);
            float gf = sigmoid_f(s_g1[64 + k]);
            float gg = tanh_f   (s_g1[128 + k]);
            float go = sigmoid_f(s_g1[192 + k]);
            c1 = fmaf(gf, c1, gi * gg);
            h1cur = go * tanh_f(c1);
        }
        if (wv == 0) ((float*)s_h1)[k] = h1cur;
        if (wv == 1) op[(size_t)t * HID] = h1cur;   // out1[b,t,k], 256B coalesced
        __syncthreads();   // (4) new h1 visible before next step reads it
    }

    // ---- final states: h_n [2,B,H] then c_n [2,B,H] after out1 ----
    if (wv == 0) {
        const size_t BTH = (size_t)B * T_STEPS * HID;
        const size_t BH  = (size_t)B * HID;
        out[BTH + (size_t)b * HID + k]            = h0cur;
        out[BTH + BH + (size_t)b * HID + k]       = h1cur;
        out[BTH + 2 * BH + (size_t)b * HID + k]   = c0;
        out[BTH + 3 * BH + (size_t)b * HID + k]   = c1;
    }
}

extern "C" void kernel_launch(void* const* d_in, const int* in_sizes, int n_in,
                              void* d_out, int out_size, void* d_ws, size_t ws_size,
                              hipStream_t stream) {
    const float* x    = (const float*)d_in[0];
    const float* wih0 = (const float*)d_in[1];
    const float* whh0 = (const float*)d_in[2];
    const float* bih0 = (const float*)d_in[3];
    const float* bhh0 = (const float*)d_in[4];
    const float* wih1 = (const float*)d_in[5];
    const float* whh1 = (const float*)d_in[6];
    const float* bih1 = (const float*)d_in[7];
    const float* bhh1 = (const float*)d_in[8];
    float* out = (float*)d_out;

    const int B = in_sizes[0] / (T_STEPS * 4);   // 512

    lstm2_fused<<<dim3(B), dim3(256), 0, stream>>>(
        x, wih0, whh0, bih0, bhh0, wih1, whh1, bih1, bhh1, out, B);
}

// Round 2
// 4619.975 us; speedup vs baseline: 1.0001x; 1.0001x over previous
//
#include <hip/hip_runtime.h>

#define T_STEPS 2048
#define HID 64
#define GATES 256

__device__ __forceinline__ float sigmoid_f(float x) {
    float e = __expf(-x);                    // v_exp_f32 path; saturates correctly at +-inf
    return __fdividef(1.0f, 1.0f + e);
}

__device__ __forceinline__ float tanh_f(float x) {
    float xc = fminf(fmaxf(x, -15.0f), 15.0f);
    float e = __expf(2.0f * xc);             // e in [e^-30, e^30], no overflow
    return __fdividef(e - 1.0f, e + 1.0f);
}

// One block per batch element. 256 threads: thread g computes gate g (i,f,g,o x 64).
// Weights live in registers (~224 VGPR/thread). h0/h1 broadcast via LDS.
// c0/c1 kept redundantly in registers of every wave (deterministic).
//
// amdgpu_waves_per_eu(2,2): grid = 512 blocks = 2 blocks/CU = 2 waves/SIMD, so
// occupancy >2 waves/EU is unreachable. Without the max=2 pin the backend
// squeezes to the 128-VGPR tier (R0: VGPR_Count=124) and spills all 192
// weight registers to scratch -> 5.1 ms. Pin gives budget 256, no spills.
__global__ void __launch_bounds__(256) __attribute__((amdgpu_waves_per_eu(2, 2)))
lstm2_fused(
    const float* __restrict__ x,
    const float* __restrict__ wih0, const float* __restrict__ whh0,
    const float* __restrict__ bih0, const float* __restrict__ bhh0,
    const float* __restrict__ wih1, const float* __restrict__ whh1,
    const float* __restrict__ bih1, const float* __restrict__ bhh1,
    float* __restrict__ out, int B)
{
    __shared__ float4 s_x[T_STEPS];      // 32 KB: whole input row x[b]
    __shared__ float4 s_h0[HID / 4];     // layer0 hidden state
    __shared__ float4 s_h1[HID / 4];     // layer1 hidden state
    __shared__ float  s_g0[GATES];       // layer0 pre-activation gates
    __shared__ float  s_g1[GATES];       // layer1 pre-activation gates

    const int tid = threadIdx.x;
    const int k  = tid & 63;            // hidden unit
    const int wv = tid >> 6;            // gate type (0=i,1=f,2=g,3=o)
    const int g  = tid;                 // gate row index
    const int b  = blockIdx.x;

    // ---- stage x[b] into LDS (2048 float4 = 32 KB, coalesced) ----
    const float4* xb = (const float4*)(x + (size_t)b * (T_STEPS * 4));
    for (int i = tid; i < T_STEPS; i += 256) s_x[i] = xb[i];
    if (tid < HID / 4)           s_h0[tid]           = make_float4(0.f, 0.f, 0.f, 0.f);
    else if (tid < HID / 2)      s_h1[tid - HID / 4] = make_float4(0.f, 0.f, 0.f, 0.f);

    // ---- load this thread's weight rows into registers ----
    float4 wi0 = ((const float4*)wih0)[g];   // w_ih_l0 row g: 4 floats
    float4 wh0[16], wi1[16], wh1[16];
    #pragma unroll
    for (int jj = 0; jj < 16; ++jj) {
        wh0[jj] = ((const float4*)whh0)[g * 16 + jj];
        wi1[jj] = ((const float4*)wih1)[g * 16 + jj];
        wh1[jj] = ((const float4*)whh1)[g * 16 + jj];
    }
    const float bias0 = bih0[g] + bhh0[g];
    const float bias1 = bih1[g] + bhh1[g];

    float c0 = 0.f, c1 = 0.f, h0cur = 0.f, h1cur = 0.f;
    float* op = out + (size_t)b * T_STEPS * HID + k;   // out1[b, t, k]

    __syncthreads();

    for (int t = 0; t < T_STEPS; ++t) {
        // ---------- Phase A: layer0 gates ----------
        float4 xt = s_x[t];
        float a0 = fmaf(wi0.x, xt.x, bias0);
        a0 = fmaf(wi0.y, xt.y, a0);
        a0 = fmaf(wi0.z, xt.z, a0);
        a0 = fmaf(wi0.w, xt.w, a0);
        float a1 = 0.f;
        #pragma unroll
        for (int jj = 0; jj < 16; jj += 2) {
            float4 h = s_h0[jj];
            a0 = fmaf(wh0[jj].x, h.x, a0);
            a0 = fmaf(wh0[jj].y, h.y, a0);
            a0 = fmaf(wh0[jj].z, h.z, a0);
            a0 = fmaf(wh0[jj].w, h.w, a0);
            float4 h2 = s_h0[jj + 1];
            a1 = fmaf(wh0[jj + 1].x, h2.x, a1);
            a1 = fmaf(wh0[jj + 1].y, h2.y, a1);
            a1 = fmaf(wh0[jj + 1].z, h2.z, a1);
            a1 = fmaf(wh0[jj + 1].w, h2.w, a1);
        }
        s_g0[g] = a0 + a1;
        __syncthreads();   // (1) gates0 visible; s_h0 reads done

        // ---------- Phase B: layer0 activations (all waves, redundant) ----------
        {
            float gi = sigmoid_f(s_g0[k]);
            float gf = sigmoid_f(s_g0[64 + k]);
            float gg = tanh_f   (s_g0[128 + k]);
            float go = sigmoid_f(s_g0[192 + k]);
            c0 = fmaf(gf, c0, gi * gg);
            h0cur = go * tanh_f(c0);
        }
        if (wv == 0) ((float*)s_h0)[k] = h0cur;
        __syncthreads();   // (2) new h0 visible

        // ---------- Phase C: layer1 gates ----------
        float q0 = bias1, q1 = 0.f, q2 = 0.f, q3 = 0.f;
        #pragma unroll
        for (int jj = 0; jj < 16; ++jj) {
            float4 hv = s_h0[jj];
            float4 gv = s_h1[jj];
            if (jj & 1) {
                q2 = fmaf(wi1[jj].x, hv.x, q2);
                q2 = fmaf(wi1[jj].y, hv.y, q2);
                q2 = fmaf(wi1[jj].z, hv.z, q2);
                q2 = fmaf(wi1[jj].w, hv.w, q2);
                q3 = fmaf(wh1[jj].x, gv.x, q3);
                q3 = fmaf(wh1[jj].y, gv.y, q3);
                q3 = fmaf(wh1[jj].z, gv.z, q3);
                q3 = fmaf(wh1[jj].w, gv.w, q3);
            } else {
                q0 = fmaf(wi1[jj].x, hv.x, q0);
                q0 = fmaf(wi1[jj].y, hv.y, q0);
                q0 = fmaf(wi1[jj].z, hv.z, q0);
                q0 = fmaf(wi1[jj].w, hv.w, q0);
                q1 = fmaf(wh1[jj].x, gv.x, q1);
                q1 = fmaf(wh1[jj].y, gv.y, q1);
                q1 = fmaf(wh1[jj].z, gv.z, q1);
                q1 = fmaf(wh1[jj].w, gv.w, q1);
            }
        }
        s_g1[g] = (q0 + q1) + (q2 + q3);
        __syncthreads();   // (3) gates1 visible; s_h1 reads done

        // ---------- Phase D: layer1 activations ----------
        {
            float gi = sigmoid_f(s_g1[k]);
            float gf = sigmoid_f(s_g1[64 + k]);
            float gg = tanh_f   (s_g1[128 + k]);
            float go = sigmoid_f(s_g1[192 + k]);
            c1 = fmaf(gf, c1, gi * gg);
            h1cur = go * tanh_f(c1);
        }
        if (wv == 0) ((float*)s_h1)[k] = h1cur;
        if (wv == 1) op[(size_t)t * HID] = h1cur;   // out1[b,t,k], 256B coalesced
        __syncthreads();   // (4) new h1 visible before next step reads it
    }

    // ---- final states: h_n [2,B,H] then c_n [2,B,H] after out1 ----
    if (wv == 0) {
        const size_t BTH = (size_t)B * T_STEPS * HID;
        const size_t BH  = (size_t)B * HID;
        out[BTH + (size_t)b * HID + k]            = h0cur;
        out[BTH + BH + (size_t)b * HID + k]       = h1cur;
        out[BTH + 2 * BH + (size_t)b * HID + k]   = c0;
        out[BTH + 3 * BH + (size_t)b * HID + k]   = c1;
    }
}

extern "C" void kernel_launch(void* const* d_in, const int* in_sizes, int n_in,
                              void* d_out, int out_size, void* d_ws, size_t ws_size,
                              hipStream_t stream) {
    const float* x    = (const float*)d_in[0];
    const float* wih0 = (const float*)d_in[1];
    const float* whh0 = (const float*)d_in[2];
    const float* bih0 = (const float*)d_in[3];
    const float* bhh0 = (const float*)d_in[4];
    const float* wih1 = (const float*)d_in[5];
    const float* whh1 = (const float*)d_in[6];
    const float* bih1 = (const float*)d_in[7];
    const float* bhh1 = (const float*)d_in[8];
    float* out = (float*)d_out;

    const int B = in_sizes[0] / (T_STEPS * 4);   // 512

    lstm2_fused<<<dim3(B), dim3(256), 0, stream>>>(
        x, wih0, whh0, bih0, bhh0, wih1, whh1, bih1, bhh1, out, B);
}

// Round 3
// 2970.146 us; speedup vs baseline: 1.5556x; 1.5555x over previous
//
#include <hip/hip_runtime.h>

#define T_STEPS 2048
#define HID 64

typedef __attribute__((ext_vector_type(8))) short short8;
typedef __attribute__((ext_vector_type(4))) float f32x4;

static __device__ __forceinline__ unsigned short f2bf(float f) {
    unsigned int u = __float_as_uint(f);
    u = u + 0x7fffu + ((u >> 16) & 1u);   // RNE; inputs are finite
    return (unsigned short)(u >> 16);
}
static __device__ __forceinline__ float sigmoid_f(float x) {
    float e = __expf(-x);
    return __fdividef(1.0f, 1.0f + e);
}
static __device__ __forceinline__ float tanh_f(float x) {
    float xc = fminf(fmaxf(x, -15.0f), 15.0f);
    float e = __expf(2.0f * xc);
    return 1.0f - __fdividef(2.0f, e + 1.0f);
}

// One block per batch element (512 blocks, 2 blocks/CU). 4 waves.
// Wave w owns gate Mtiles {w, 4+w, 8+w, 12+w} (i,f,g,o rows 16w..16w+15).
// Weights live as bf16 MFMA A-fragments in registers (~112 VGPR).
// layer0: K=96 = [h0(64) | x_t(4) pad32] -> 3 ktiles. layer1: K=128 = [h0|h1] -> 4 ktiles.
// B-fragments: every lane reads the same h[k] slice -> all 16 C columns equal,
// so column 0 (read by lanes lane&15==0) is the matvec result.
// Activations: per-lane k = lane&63, redundant across waves (deterministic);
// c-state lives in registers of every wave.
__global__ void __launch_bounds__(256, 2) lstm2_mfma(
    const float* __restrict__ x,
    const float* __restrict__ wih0, const float* __restrict__ whh0,
    const float* __restrict__ bih0, const float* __restrict__ bhh0,
    const float* __restrict__ wih1, const float* __restrict__ whh1,
    const float* __restrict__ bih1, const float* __restrict__ bhh1,
    float* __restrict__ out, int B)
{
    __shared__ __align__(16) unsigned short s_h0[HID];   // h0 as bf16
    __shared__ __align__(16) unsigned short s_h1[HID];   // h1 as bf16
    __shared__ __align__(16) unsigned short s_xk[32];    // [x_t(4) | zeros] as bf16
    __shared__ __align__(16) float s_g0[256];            // layer0 pre-act gates (f32)
    __shared__ __align__(16) float s_g1[256];

    const int tid  = threadIdx.x;
    const int lane = tid & 63;
    const int w    = tid >> 6;      // wave 0..3
    const int l15  = lane & 15;
    const int lg   = lane >> 4;     // 0..3
    const int b    = blockIdx.x;

    // ---------------- load weights as A-fragments (once) ----------------
    // A layout assumption (consistent A/B -> k-order cancels): row m = l15,
    // k = kt*32 + lg*8 + j.  C/D: col = l15, row = lg*4 + r (m89-verified).
    short8 A0[4][3];   // layer0: kt0/kt1 = Whh0, kt2 = [Wih0 | 0]
    short8 A1[4][4];   // layer1: kt0/kt1 = Wih1 (acts on h0), kt2/kt3 = Whh1 (h1)
    f32x4  b0v[4], b1v[4];
    #pragma unroll
    for (int mi = 0; mi < 4; ++mi) {
        const int mt = w + 4 * mi;          // Mtile index
        const int ga = 16 * mt + l15;       // gate row for A-frags
        #pragma unroll
        for (int kt = 0; kt < 2; ++kt)
            #pragma unroll
            for (int j = 0; j < 8; ++j)
                A0[mi][kt][j] = (short)f2bf(whh0[ga * HID + kt * 32 + lg * 8 + j]);
        #pragma unroll
        for (int j = 0; j < 8; ++j) {
            const int kl = lg * 8 + j;      // 0..31 within ktile2
            A0[mi][2][j] = (kl < 4) ? (short)f2bf(wih0[ga * 4 + kl]) : (short)0;
        }
        #pragma unroll
        for (int kt = 0; kt < 2; ++kt)
            #pragma unroll
            for (int j = 0; j < 8; ++j)
                A1[mi][kt][j] = (short)f2bf(wih1[ga * HID + kt * 32 + lg * 8 + j]);
        #pragma unroll
        for (int kt = 0; kt < 2; ++kt)
            #pragma unroll
            for (int j = 0; j < 8; ++j)
                A1[mi][2 + kt][j] = (short)f2bf(whh1[ga * HID + kt * 32 + lg * 8 + j]);
        #pragma unroll
        for (int r = 0; r < 4; ++r) {
            const int gc = 16 * mt + lg * 4 + r;    // gate row for C rows
            b0v[mi][r] = bih0[gc] + bhh0[gc];
            b1v[mi][r] = bih1[gc] + bhh1[gc];
        }
    }

    // ---------------- init LDS state ----------------
    const float* __restrict__ xb = x + (size_t)b * (T_STEPS * 4);
    if (tid < HID) { s_h0[tid] = 0; s_h1[tid] = 0; }
    if (tid < 32)  s_xk[tid] = (tid < 4) ? f2bf(xb[tid]) : (unsigned short)0;
    __syncthreads();

    float c0 = 0.f, c1 = 0.f, h0f = 0.f, h1f = 0.f;
    float* __restrict__ op = out + (size_t)b * T_STEPS * HID + lane;

    for (int t = 0; t < T_STEPS; ++t) {
        // prefetch next x (wave-uniform scalar-ish loads)
        const float* xp = xb + ((t + 1 < T_STEPS) ? (t + 1) : t) * 4;
        const float xn0 = xp[0], xn1 = xp[1], xn2 = xp[2], xn3 = xp[3];

        // ---------- layer0 MFMA: gates0 = Whh0*h0 + Wih0*x + b ----------
        short8 Bh0a = ((const short8*)s_h0)[lg];       // k 0..31
        short8 Bh0b = ((const short8*)s_h0)[4 + lg];   // k 32..63
        short8 Bx   = ((const short8*)s_xk)[lg & 3];   // k 64..95 ([x|0])
        f32x4 acc[4];
        #pragma unroll
        for (int mi = 0; mi < 4; ++mi) acc[mi] = b0v[mi];
        #pragma unroll
        for (int mi = 0; mi < 4; ++mi) {
            acc[mi] = __builtin_amdgcn_mfma_f32_16x16x32_bf16(A0[mi][0], Bh0a, acc[mi], 0, 0, 0);
            acc[mi] = __builtin_amdgcn_mfma_f32_16x16x32_bf16(A0[mi][1], Bh0b, acc[mi], 0, 0, 0);
            acc[mi] = __builtin_amdgcn_mfma_f32_16x16x32_bf16(A0[mi][2], Bx,   acc[mi], 0, 0, 0);
        }
        if (l15 == 0) {
            #pragma unroll
            for (int mi = 0; mi < 4; ++mi)
                *(f32x4*)&s_g0[16 * (w + 4 * mi) + 4 * lg] = acc[mi];
        }
        __syncthreads();   // (1) gates0 visible; s_h0/s_xk reads done

        // ---------- layer0 activations (per-lane k = lane, redundant/wave) ----------
        {
            float gi = sigmoid_f(s_g0[lane]);
            float gf = sigmoid_f(s_g0[64 + lane]);
            float gg = tanh_f   (s_g0[128 + lane]);
            float go = sigmoid_f(s_g0[192 + lane]);
            c0  = fmaf(gf, c0, gi * gg);
            h0f = go * tanh_f(c0);
        }
        if (w == 0) s_h0[lane] = f2bf(h0f);
        if (w == 3 && lane < 16) {   // stage x_{t+1} for next step
            float xv = (lane & 2) ? ((lane & 1) ? xn3 : xn2)
                                  : ((lane & 1) ? xn1 : xn0);
            s_xk[lane] = (lane < 4) ? f2bf(xv) : (unsigned short)0;
        }
        __syncthreads();   // (2) new h0 + next x staged

        // ---------- layer1 MFMA: gates1 = Wih1*h0 + Whh1*h1 + b ----------
        short8 Ch0a = ((const short8*)s_h0)[lg];
        short8 Ch0b = ((const short8*)s_h0)[4 + lg];
        short8 Ch1a = ((const short8*)s_h1)[lg];
        short8 Ch1b = ((const short8*)s_h1)[4 + lg];
        f32x4 acc1[4];
        #pragma unroll
        for (int mi = 0; mi < 4; ++mi) acc1[mi] = b1v[mi];
        #pragma unroll
        for (int mi = 0; mi < 4; ++mi) {
            acc1[mi] = __builtin_amdgcn_mfma_f32_16x16x32_bf16(A1[mi][0], Ch0a, acc1[mi], 0, 0, 0);
            acc1[mi] = __builtin_amdgcn_mfma_f32_16x16x32_bf16(A1[mi][1], Ch0b, acc1[mi], 0, 0, 0);
            acc1[mi] = __builtin_amdgcn_mfma_f32_16x16x32_bf16(A1[mi][2], Ch1a, acc1[mi], 0, 0, 0);
            acc1[mi] = __builtin_amdgcn_mfma_f32_16x16x32_bf16(A1[mi][3], Ch1b, acc1[mi], 0, 0, 0);
        }
        if (l15 == 0) {
            #pragma unroll
            for (int mi = 0; mi < 4; ++mi)
                *(f32x4*)&s_g1[16 * (w + 4 * mi) + 4 * lg] = acc1[mi];
        }
        __syncthreads();   // (3) gates1 visible; s_h0/s_h1 reads done

        // ---------- layer1 activations ----------
        {
            float gi = sigmoid_f(s_g1[lane]);
            float gf = sigmoid_f(s_g1[64 + lane]);
            float gg = tanh_f   (s_g1[128 + lane]);
            float go = sigmoid_f(s_g1[192 + lane]);
            c1  = fmaf(gf, c1, gi * gg);
            h1f = go * tanh_f(c1);
        }
        if (w == 0) s_h1[lane] = f2bf(h1f);
        if (w == 1) op[(size_t)t * HID] = h1f;   // out1[b,t,k] f32, 256B coalesced
        __syncthreads();   // (4) new h1 visible before next step
    }

    // ---------------- final states: h_n [2,B,H], c_n [2,B,H] ----------------
    if (w == 0) {
        const size_t BTH = (size_t)B * T_STEPS * HID;
        const size_t BH  = (size_t)B * HID;
        out[BTH + (size_t)b * HID + lane]           = h0f;
        out[BTH + BH + (size_t)b * HID + lane]      = h1f;
        out[BTH + 2 * BH + (size_t)b * HID + lane]  = c0;
        out[BTH + 3 * BH + (size_t)b * HID + lane]  = c1;
    }
}

extern "C" void kernel_launch(void* const* d_in, const int* in_sizes, int n_in,
                              void* d_out, int out_size, void* d_ws, size_t ws_size,
                              hipStream_t stream) {
    const float* x    = (const float*)d_in[0];
    const float* wih0 = (const float*)d_in[1];
    const float* whh0 = (const float*)d_in[2];
    const float* bih0 = (const float*)d_in[3];
    const float* bhh0 = (const float*)d_in[4];
    const float* wih1 = (const float*)d_in[5];
    const float* whh1 = (const float*)d_in[6];
    const float* bih1 = (const float*)d_in[7];
    const float* bhh1 = (const float*)d_in[8];
    float* out = (float*)d_out;

    const int B = in_sizes[0] / (T_STEPS * 4);   // 512

    lstm2_mfma<<<dim3(B), dim3(256), 0, stream>>>(
        x, wih0, whh0, bih0, bhh0, wih1, whh1, bih1, bhh1, out, B);
}

// Round 4
// 2301.124 us; speedup vs baseline: 2.0079x; 1.2907x over previous
//
#include <hip/hip_runtime.h>

#define T_STEPS 2048
#define HID 64

typedef __attribute__((ext_vector_type(8))) short short8;
typedef __attribute__((ext_vector_type(4))) short short4v;
typedef __attribute__((ext_vector_type(4))) float f32x4;
typedef __attribute__((ext_vector_type(4))) unsigned short ushort4v;

static __device__ __forceinline__ unsigned short f2bf(float f) {
    unsigned int u = __float_as_uint(f);
    u = u + 0x7fffu + ((u >> 16) & 1u);   // RNE; inputs finite
    return (unsigned short)(u >> 16);
}
static __device__ __forceinline__ float sigmoid_f(float x) {
    float e = __expf(-x);
    return __fdividef(1.0f, 1.0f + e);
}
static __device__ __forceinline__ float tanh_f(float x) {
    float xc = fminf(fmaxf(x, -15.0f), 15.0f);
    float e = __expf(2.0f * xc);
    return 1.0f - __fdividef(2.0f, e + 1.0f);
}

// One block per batch element (512 blocks, 2 blocks/CU), 4 waves.
// SWAPPED MFMA: A = h broadcast across rows (rows of C identical),
// B = W^T (col = gate row). Lane (lg,l15) then holds gate-type ni for
// unit u = 16*w + l15 at acc[ni][0] -- STATIC index, i/f/g/o all on one
// lane -> in-register activations, no gate LDS round-trip.
// 2 barriers/step (was 4). x pre-staged to LDS as bf16 (16 KB).
// h0/h1 ping-pong (2 buffers) so read(t-1)/write(t) never race.
__global__ void __launch_bounds__(256, 2) lstm2_mfma_swap(
    const float* __restrict__ x,
    const float* __restrict__ wih0, const float* __restrict__ whh0,
    const float* __restrict__ bih0, const float* __restrict__ bhh0,
    const float* __restrict__ wih1, const float* __restrict__ whh1,
    const float* __restrict__ bih1, const float* __restrict__ bhh1,
    float* __restrict__ out, int B)
{
    __shared__ __align__(16) unsigned short s_x[T_STEPS * 4];  // 16 KB bf16
    __shared__ __align__(16) unsigned short s_h0[2][HID];      // ping-pong h0
    __shared__ __align__(16) unsigned short s_h1[2][HID];      // ping-pong h1

    const int tid  = threadIdx.x;
    const int lane = tid & 63;
    const int w    = tid >> 6;      // wave 0..3
    const int l15  = lane & 15;
    const int lg   = lane >> 4;     // 0..3 (k-block)
    const int b    = blockIdx.x;

    // ---------------- W^T B-fragments in registers (once) ----------------
    // B-frag slot (lg, j) of tile nt holds W[16*nt + l15, kt*32 + lg*8 + j].
    // A uses the same (lg,j)->k map, so any true intra-k permutation cancels.
    short8 W0[4][3];   // layer0: kt0/kt1 = Whh0 (k=h0), kt2 = [Wih0 | 0] (k=x)
    short8 W1[4][4];   // layer1: kt0/kt1 = Wih1 (k=h0), kt2/kt3 = Whh1 (k=h1)
    float  b0s[4], b1s[4];
    #pragma unroll
    for (int ni = 0; ni < 4; ++ni) {
        const int nt = w + 4 * ni;         // Ntile: gate-type ni, units 16w..16w+15
        const int g  = 16 * nt + l15;      // this lane's gate row
        #pragma unroll
        for (int kt = 0; kt < 2; ++kt)
            #pragma unroll
            for (int j = 0; j < 8; ++j)
                W0[ni][kt][j] = (short)f2bf(whh0[g * HID + kt * 32 + lg * 8 + j]);
        #pragma unroll
        for (int j = 0; j < 8; ++j) {
            const int kl = lg * 8 + j;
            W0[ni][2][j] = (kl < 4) ? (short)f2bf(wih0[g * 4 + kl]) : (short)0;
        }
        #pragma unroll
        for (int kt = 0; kt < 2; ++kt)
            #pragma unroll
            for (int j = 0; j < 8; ++j)
                W1[ni][kt][j] = (short)f2bf(wih1[g * HID + kt * 32 + lg * 8 + j]);
        #pragma unroll
        for (int kt = 0; kt < 2; ++kt)
            #pragma unroll
            for (int j = 0; j < 8; ++j)
                W1[ni][2 + kt][j] = (short)f2bf(whh1[g * HID + kt * 32 + lg * 8 + j]);
        b0s[ni] = bih0[g] + bhh0[g];
        b1s[ni] = bih1[g] + bhh1[g];
    }

    // ---------------- stage x[b] to LDS as bf16 (coalesced, once) ----------------
    const float4* __restrict__ xb4 = (const float4*)(x + (size_t)b * (T_STEPS * 4));
    for (int i = tid; i < T_STEPS; i += 256) {
        float4 v = xb4[i];
        ushort4v u;
        u.x = f2bf(v.x); u.y = f2bf(v.y); u.z = f2bf(v.z); u.w = f2bf(v.w);
        *(ushort4v*)&s_x[4 * i] = u;
    }
    if (tid < HID) { s_h0[1][tid] = 0; s_h1[1][tid] = 0; }
    __syncthreads();

    float c0s = 0.f, c1s = 0.f, h0s = 0.f, h1s = 0.f;
    const int u = 16 * w + l15;                 // this lane's hidden unit
    float* __restrict__ op = out + (size_t)b * T_STEPS * HID + u;

    for (int t = 0; t < T_STEPS; ++t) {
        const int p = t & 1, q = p ^ 1;

        // ---------- layer0: gates = [h0(t-1) | x_t] . W0^T + b ----------
        short8 Ah0a = *(const short8*)&s_h0[q][lg * 8];        // k 0..31
        short8 Ah0b = *(const short8*)&s_h0[q][32 + lg * 8];   // k 32..63
        short4v xs = *(const short4v*)&s_x[4 * t];             // uniform broadcast
        short8 Ax;
        Ax[0] = (lg == 0) ? xs[0] : (short)0;
        Ax[1] = (lg == 0) ? xs[1] : (short)0;
        Ax[2] = (lg == 0) ? xs[2] : (short)0;
        Ax[3] = (lg == 0) ? xs[3] : (short)0;
        Ax[4] = 0; Ax[5] = 0; Ax[6] = 0; Ax[7] = 0;

        f32x4 acc0, acc1, acc2, acc3;
        acc0 = (f32x4){b0s[0], b0s[0], b0s[0], b0s[0]};
        acc1 = (f32x4){b0s[1], b0s[1], b0s[1], b0s[1]};
        acc2 = (f32x4){b0s[2], b0s[2], b0s[2], b0s[2]};
        acc3 = (f32x4){b0s[3], b0s[3], b0s[3], b0s[3]};
        acc0 = __builtin_amdgcn_mfma_f32_16x16x32_bf16(Ah0a, W0[0][0], acc0, 0, 0, 0);
        acc1 = __builtin_amdgcn_mfma_f32_16x16x32_bf16(Ah0a, W0[1][0], acc1, 0, 0, 0);
        acc2 = __builtin_amdgcn_mfma_f32_16x16x32_bf16(Ah0a, W0[2][0], acc2, 0, 0, 0);
        acc3 = __builtin_amdgcn_mfma_f32_16x16x32_bf16(Ah0a, W0[3][0], acc3, 0, 0, 0);
        acc0 = __builtin_amdgcn_mfma_f32_16x16x32_bf16(Ah0b, W0[0][1], acc0, 0, 0, 0);
        acc1 = __builtin_amdgcn_mfma_f32_16x16x32_bf16(Ah0b, W0[1][1], acc1, 0, 0, 0);
        acc2 = __builtin_amdgcn_mfma_f32_16x16x32_bf16(Ah0b, W0[2][1], acc2, 0, 0, 0);
        acc3 = __builtin_amdgcn_mfma_f32_16x16x32_bf16(Ah0b, W0[3][1], acc3, 0, 0, 0);
        acc0 = __builtin_amdgcn_mfma_f32_16x16x32_bf16(Ax,   W0[0][2], acc0, 0, 0, 0);
        acc1 = __builtin_amdgcn_mfma_f32_16x16x32_bf16(Ax,   W0[1][2], acc1, 0, 0, 0);
        acc2 = __builtin_amdgcn_mfma_f32_16x16x32_bf16(Ax,   W0[2][2], acc2, 0, 0, 0);
        acc3 = __builtin_amdgcn_mfma_f32_16x16x32_bf16(Ax,   W0[3][2], acc3, 0, 0, 0);

        // ---------- layer0 activation (per-lane, static indices) ----------
        {
            float i_ = sigmoid_f(acc0[0]);
            float f_ = sigmoid_f(acc1[0]);
            float g_ = tanh_f   (acc2[0]);
            float o_ = sigmoid_f(acc3[0]);
            c0s = fmaf(f_, c0s, i_ * g_);
            h0s = o_ * tanh_f(c0s);
        }
        if (lg == 0) s_h0[p][u] = f2bf(h0s);
        __syncthreads();   // (1) h0(t) visible

        // ---------- layer1: gates = [h0(t) | h1(t-1)] . W1^T + b ----------
        short8 Bh0a = *(const short8*)&s_h0[p][lg * 8];
        short8 Bh0b = *(const short8*)&s_h0[p][32 + lg * 8];
        short8 Bh1a = *(const short8*)&s_h1[q][lg * 8];
        short8 Bh1b = *(const short8*)&s_h1[q][32 + lg * 8];

        f32x4 d0, d1, d2, d3;
        d0 = (f32x4){b1s[0], b1s[0], b1s[0], b1s[0]};
        d1 = (f32x4){b1s[1], b1s[1], b1s[1], b1s[1]};
        d2 = (f32x4){b1s[2], b1s[2], b1s[2], b1s[2]};
        d3 = (f32x4){b1s[3], b1s[3], b1s[3], b1s[3]};
        d0 = __builtin_amdgcn_mfma_f32_16x16x32_bf16(Bh0a, W1[0][0], d0, 0, 0, 0);
        d1 = __builtin_amdgcn_mfma_f32_16x16x32_bf16(Bh0a, W1[1][0], d1, 0, 0, 0);
        d2 = __builtin_amdgcn_mfma_f32_16x16x32_bf16(Bh0a, W1[2][0], d2, 0, 0, 0);
        d3 = __builtin_amdgcn_mfma_f32_16x16x32_bf16(Bh0a, W1[3][0], d3, 0, 0, 0);
        d0 = __builtin_amdgcn_mfma_f32_16x16x32_bf16(Bh0b, W1[0][1], d0, 0, 0, 0);
        d1 = __builtin_amdgcn_mfma_f32_16x16x32_bf16(Bh0b, W1[1][1], d1, 0, 0, 0);
        d2 = __builtin_amdgcn_mfma_f32_16x16x32_bf16(Bh0b, W1[2][1], d2, 0, 0, 0);
        d3 = __builtin_amdgcn_mfma_f32_16x16x32_bf16(Bh0b, W1[3][1], d3, 0, 0, 0);
        d0 = __builtin_amdgcn_mfma_f32_16x16x32_bf16(Bh1a, W1[0][2], d0, 0, 0, 0);
        d1 = __builtin_amdgcn_mfma_f32_16x16x32_bf16(Bh1a, W1[1][2], d1, 0, 0, 0);
        d2 = __builtin_amdgcn_mfma_f32_16x16x32_bf16(Bh1a, W1[2][2], d2, 0, 0, 0);
        d3 = __builtin_amdgcn_mfma_f32_16x16x32_bf16(Bh1a, W1[3][2], d3, 0, 0, 0);
        d0 = __builtin_amdgcn_mfma_f32_16x16x32_bf16(Bh1b, W1[0][3], d0, 0, 0, 0);
        d1 = __builtin_amdgcn_mfma_f32_16x16x32_bf16(Bh1b, W1[1][3], d1, 0, 0, 0);
        d2 = __builtin_amdgcn_mfma_f32_16x16x32_bf16(Bh1b, W1[2][3], d2, 0, 0, 0);
        d3 = __builtin_amdgcn_mfma_f32_16x16x32_bf16(Bh1b, W1[3][3], d3, 0, 0, 0);

        // ---------- layer1 activation ----------
        {
            float i_ = sigmoid_f(d0[0]);
            float f_ = sigmoid_f(d1[0]);
            float g_ = tanh_f   (d2[0]);
            float o_ = sigmoid_f(d3[0]);
            c1s = fmaf(f_, c1s, i_ * g_);
            h1s = o_ * tanh_f(c1s);
        }
        if (lg == 0) {
            s_h1[p][u] = f2bf(h1s);
            op[(size_t)t * HID] = h1s;   // out1[b,t,u]: 64 consecutive dwords/block
        }
        __syncthreads();   // (2) h1(t) visible before next step
    }

    // ---------------- final states: h_n [2,B,H], c_n [2,B,H] ----------------
    if (lg == 0) {
        const size_t BTH = (size_t)B * T_STEPS * HID;
        const size_t BH  = (size_t)B * HID;
        out[BTH + (size_t)b * HID + u]           = h0s;
        out[BTH + BH + (size_t)b * HID + u]      = h1s;
        out[BTH + 2 * BH + (size_t)b * HID + u]  = c0s;
        out[BTH + 3 * BH + (size_t)b * HID + u]  = c1s;
    }
}

extern "C" void kernel_launch(void* const* d_in, const int* in_sizes, int n_in,
                              void* d_out, int out_size, void* d_ws, size_t ws_size,
                              hipStream_t stream) {
    const float* x    = (const float*)d_in[0];
    const float* wih0 = (const float*)d_in[1];
    const float* whh0 = (const float*)d_in[2];
    const float* bih0 = (const float*)d_in[3];
    const float* bhh0 = (const float*)d_in[4];
    const float* wih1 = (const float*)d_in[5];
    const float* whh1 = (const float*)d_in[6];
    const float* bih1 = (const float*)d_in[7];
    const float* bhh1 = (const float*)d_in[8];
    float* out = (float*)d_out;

    const int B = in_sizes[0] / (T_STEPS * 4);   // 512

    lstm2_mfma_swap<<<dim3(B), dim3(256), 0, stream>>>(
        x, wih0, whh0, bih0, bhh0, wih1, whh1, bih1, bhh1, out, B);
}

// Round 5
// 2153.446 us; speedup vs baseline: 2.1456x; 1.0686x over previous
//
#include <hip/hip_runtime.h>

#define T_STEPS 2048
#define HID 64

typedef __attribute__((ext_vector_type(8))) short short8;
typedef __attribute__((ext_vector_type(4))) float f32x4;

static __device__ __forceinline__ unsigned short f2bf(float f) {
    unsigned int u = __float_as_uint(f);
    u = u + 0x7fffu + ((u >> 16) & 1u);   // RNE; inputs finite
    return (unsigned short)(u >> 16);
}
static __device__ __forceinline__ float sigmoid_f(float x) {
    float e = __expf(-x);
    return __fdividef(1.0f, 1.0f + e);
}
static __device__ __forceinline__ float tanh_f(float x) {
    float xc = fminf(fmaxf(x, -15.0f), 15.0f);   // clamp needed: c-state can grow
    float e = __expf(2.0f * xc);
    return 1.0f - __fdividef(2.0f, e + 1.0f);
}

// One block per batch element (512 blocks, 2 blocks/CU), 4 waves.
// Layer-fused software pipeline: iteration i computes L0 -> h0(i) AND
// L1 -> h1(i-1) in ONE phase (they share the h0(i-1) fragment read), with
// ONE raw s_barrier per step (lgkmcnt-only wait: out1 global stores stay
// in flight -- __syncthreads would drain vmcnt(0) every step).
// Wih0*x (K=4) is 16 scalar f32 FMAs, not an MFMA tile.
// Gate layout: swapped MFMA (A = h replicated rows, B = W^T), lane (lg,l15)
// holds gate-type ni of unit u=16w+l15 at acc[ni][0] -- static index.
__global__ void __launch_bounds__(256, 2) __attribute__((amdgpu_waves_per_eu(2, 2)))
lstm2_pipe(const float* __restrict__ x,
           const float* __restrict__ wih0, const float* __restrict__ whh0,
           const float* __restrict__ bih0, const float* __restrict__ bhh0,
           const float* __restrict__ wih1, const float* __restrict__ whh1,
           const float* __restrict__ bih1, const float* __restrict__ bhh1,
           float* __restrict__ out, int B)
{
    __shared__ __align__(16) float s_xf[T_STEPS * 4];        // 32 KB, f32
    __shared__ __align__(16) unsigned short s_h0[2][HID];    // ping-pong h0 (bf16)
    __shared__ __align__(16) unsigned short s_h1[2][HID];    // ping-pong h1 (bf16)

    const int tid  = threadIdx.x;
    const int lane = tid & 63;
    const int w    = tid >> 6;      // wave 0..3 -> units 16w..16w+15
    const int l15  = lane & 15;
    const int lg   = lane >> 4;     // 0..3 (k-block)
    const int b    = blockIdx.x;

    // ---------------- W^T B-fragments in registers (once) ----------------
    short8 W0[4][2];   // Whh0 (k = h0), 2 ktiles
    short8 W1[4][4];   // kt0/1 = Wih1 (k = h0), kt2/3 = Whh1 (k = h1)
    float  wx[4][4];   // Wih0 rows, f32 (K=4 handled on VALU)
    float  b0s[4], b1s[4];
    #pragma unroll
    for (int ni = 0; ni < 4; ++ni) {
        const int g = 16 * (w + 4 * ni) + l15;   // this lane's gate row
        #pragma unroll
        for (int kt = 0; kt < 2; ++kt)
            #pragma unroll
            for (int j = 0; j < 8; ++j) {
                W0[ni][kt][j]     = (short)f2bf(whh0[g * HID + kt * 32 + lg * 8 + j]);
                W1[ni][kt][j]     = (short)f2bf(wih1[g * HID + kt * 32 + lg * 8 + j]);
                W1[ni][2 + kt][j] = (short)f2bf(whh1[g * HID + kt * 32 + lg * 8 + j]);
            }
        #pragma unroll
        for (int j = 0; j < 4; ++j) wx[ni][j] = wih0[g * 4 + j];
        b0s[ni] = bih0[g] + bhh0[g];
        b1s[ni] = bih1[g] + bhh1[g];
    }

    // ---------------- stage x[b] to LDS as f32 (coalesced, once) ----------------
    const float4* __restrict__ xb4 = (const float4*)(x + (size_t)b * (T_STEPS * 4));
    float4* s_xf4 = (float4*)s_xf;
    for (int i2 = tid; i2 < T_STEPS; i2 += 256) s_xf4[i2] = xb4[i2];
    if (tid < HID) {
        s_h0[0][tid] = 0; s_h0[1][tid] = 0;
        s_h1[0][tid] = 0; s_h1[1][tid] = 0;
    }
    __syncthreads();

    float c0s = 0.f, c1s = 0.f, h0s = 0.f, h1s = 0.f;
    const int u = 16 * w + l15;
    float* __restrict__ op = out + (size_t)b * T_STEPS * HID + u;

    auto do_L0 = [&](int t, int p, const short8& Ha, const short8& Hb) {
        const float4 xt = *(const float4*)&s_xf[4 * t];   // uniform -> broadcast
        f32x4 a[4];
        #pragma unroll
        for (int ni = 0; ni < 4; ++ni) {
            a[ni] = (f32x4){b0s[ni], b0s[ni], b0s[ni], b0s[ni]};
            a[ni] = __builtin_amdgcn_mfma_f32_16x16x32_bf16(Ha, W0[ni][0], a[ni], 0, 0, 0);
            a[ni] = __builtin_amdgcn_mfma_f32_16x16x32_bf16(Hb, W0[ni][1], a[ni], 0, 0, 0);
        }
        float ga[4];
        #pragma unroll
        for (int ni = 0; ni < 4; ++ni) {
            float s = a[ni][0];
            s = fmaf(wx[ni][0], xt.x, s);
            s = fmaf(wx[ni][1], xt.y, s);
            s = fmaf(wx[ni][2], xt.z, s);
            s = fmaf(wx[ni][3], xt.w, s);
            ga[ni] = s;
        }
        float i_ = sigmoid_f(ga[0]);
        float f_ = sigmoid_f(ga[1]);
        float g_ = tanh_f   (ga[2]);
        float o_ = sigmoid_f(ga[3]);
        c0s = fmaf(f_, c0s, i_ * g_);
        h0s = o_ * tanh_f(c0s);
        if (lg == 0) s_h0[p][u] = f2bf(h0s);
    };

    auto do_L1 = [&](int t, int p, int q, const short8& Ha, const short8& Hb) {
        const short8 Ga = *(const short8*)&s_h1[q][lg * 8];
        const short8 Gb = *(const short8*)&s_h1[q][32 + lg * 8];
        f32x4 d[4];
        #pragma unroll
        for (int ni = 0; ni < 4; ++ni) {
            d[ni] = (f32x4){b1s[ni], b1s[ni], b1s[ni], b1s[ni]};
            d[ni] = __builtin_amdgcn_mfma_f32_16x16x32_bf16(Ha, W1[ni][0], d[ni], 0, 0, 0);
            d[ni] = __builtin_amdgcn_mfma_f32_16x16x32_bf16(Hb, W1[ni][1], d[ni], 0, 0, 0);
            d[ni] = __builtin_amdgcn_mfma_f32_16x16x32_bf16(Ga, W1[ni][2], d[ni], 0, 0, 0);
            d[ni] = __builtin_amdgcn_mfma_f32_16x16x32_bf16(Gb, W1[ni][3], d[ni], 0, 0, 0);
        }
        float i_ = sigmoid_f(d[0][0]);
        float f_ = sigmoid_f(d[1][0]);
        float g_ = tanh_f   (d[2][0]);
        float o_ = sigmoid_f(d[3][0]);
        c1s = fmaf(f_, c1s, i_ * g_);
        h1s = o_ * tanh_f(c1s);
        if (lg == 0) {
            s_h1[p][u] = f2bf(h1s);
            op[(size_t)t * HID] = h1s;   // stays in flight across the raw barrier
        }
    };

    #define BAR() do { asm volatile("s_waitcnt lgkmcnt(0)" ::: "memory"); \
                       __builtin_amdgcn_s_barrier(); } while (0)

    // ---- i = 0: L0 only (h1(-1) path skipped) ----
    {
        const short8 Ha = *(const short8*)&s_h0[1][lg * 8];
        const short8 Hb = *(const short8*)&s_h0[1][32 + lg * 8];
        do_L0(0, 0, Ha, Hb);
        BAR();
    }
    // ---- main: single basic block, both layers, one barrier ----
    for (int i = 1; i < T_STEPS; ++i) {
        const int p = i & 1, q = p ^ 1;
        const short8 Ha = *(const short8*)&s_h0[q][lg * 8];        // h0(i-1)
        const short8 Hb = *(const short8*)&s_h0[q][32 + lg * 8];
        do_L0(i, p, Ha, Hb);          // h0(i)   <- h0(i-1), x(i)
        do_L1(i - 1, p, q, Ha, Hb);   // h1(i-1) <- h0(i-1), h1(i-2)
        BAR();
    }
    // ---- i = T: L1 only ----
    {
        const int p = T_STEPS & 1, q = p ^ 1;
        const short8 Ha = *(const short8*)&s_h0[q][lg * 8];        // h0(T-1)
        const short8 Hb = *(const short8*)&s_h0[q][32 + lg * 8];
        do_L1(T_STEPS - 1, p, q, Ha, Hb);
    }
    #undef BAR

    // ---------------- final states: h_n [2,B,H], c_n [2,B,H] ----------------
    if (lg == 0) {
        const size_t BTH = (size_t)B * T_STEPS * HID;
        const size_t BH  = (size_t)B * HID;
        out[BTH + (size_t)b * HID + u]           = h0s;   // h_n layer0
        out[BTH + BH + (size_t)b * HID + u]      = h1s;   // h_n layer1
        out[BTH + 2 * BH + (size_t)b * HID + u]  = c0s;   // c_n layer0
        out[BTH + 3 * BH + (size_t)b * HID + u]  = c1s;   // c_n layer1
    }
}

extern "C" void kernel_launch(void* const* d_in, const int* in_sizes, int n_in,
                              void* d_out, int out_size, void* d_ws, size_t ws_size,
                              hipStream_t stream) {
    const float* x    = (const float*)d_in[0];
    const float* wih0 = (const float*)d_in[1];
    const float* whh0 = (const float*)d_in[2];
    const float* bih0 = (const float*)d_in[3];
    const float* bhh0 = (const float*)d_in[4];
    const float* wih1 = (const float*)d_in[5];
    const float* whh1 = (const float*)d_in[6];
    const float* bih1 = (const float*)d_in[7];
    const float* bhh1 = (const float*)d_in[8];
    float* out = (float*)d_out;

    const int B = in_sizes[0] / (T_STEPS * 4);   // 512

    lstm2_pipe<<<dim3(B), dim3(256), 0, stream>>>(
        x, wih0, whh0, bih0, bhh0, wih1, whh1, bih1, bhh1, out, B);
}

// Round 6
// 1408.409 us; speedup vs baseline: 3.2806x; 1.5290x over previous
//
#include <hip/hip_runtime.h>

#define T_STEPS 2048
#define HID 64

typedef __attribute__((ext_vector_type(8))) short short8;
typedef __attribute__((ext_vector_type(4))) float f32x4;

static __device__ __forceinline__ unsigned short f2bf(float f) {
    unsigned int uu = __float_as_uint(f);
    uu = uu + 0x7fffu + ((uu >> 16) & 1u);   // RNE; inputs finite
    return (unsigned short)(uu >> 16);
}
// tanh via 2*sigma(2x)-1; v_exp/v_rcp saturate correctly -> no clamp needed.
static __device__ __forceinline__ float tanh_fast(float x) {
    float ex = __expf(-2.0f * x);
    return fmaf(2.0f, __builtin_amdgcn_rcpf(1.0f + ex), -1.0f);
}

// One block per batch element (512 blocks, 2 blocks/CU), 4 waves.
// Swapped MFMA (A = h replicated rows, B = W^T): every lane of every lg
// group holds ALL four gate pre-activations of unit u=16w+l15 (C rows are
// replicated). R5 computed activations 4x redundantly -> VALU-bound
// (VALUBusy 72%). Here lane (lg,l15) activates ONLY gate-type lg
// (branchless sigma-form: tanh = 2*sigma(2x)-1 via per-lane msel/asel/csel),
// then 3 shfl_xor (DS pipe) gather i,f,g,o onto lg0. Only lg0's c/h are
// correct; only lg0 writes (LDS h, out1, final states).
// One raw s_barrier per step (lgkmcnt-only: out1 stores stay in flight).
// MFMA accumulators init from a loop-invariant ZERO vector (C != D).
__global__ void __launch_bounds__(256, 2) __attribute__((amdgpu_waves_per_eu(2, 2)))
lstm2_dist(const float* __restrict__ x,
           const float* __restrict__ wih0, const float* __restrict__ whh0,
           const float* __restrict__ bih0, const float* __restrict__ bhh0,
           const float* __restrict__ wih1, const float* __restrict__ whh1,
           const float* __restrict__ bih1, const float* __restrict__ bhh1,
           float* __restrict__ out, int B)
{
    __shared__ __align__(16) float s_xf[T_STEPS * 4];        // 32 KB f32
    __shared__ __align__(16) unsigned short s_h0[2][HID];    // ping-pong h0 (bf16)
    __shared__ __align__(16) unsigned short s_h1[2][HID];    // ping-pong h1 (bf16)

    const int tid  = threadIdx.x;
    const int lane = tid & 63;
    const int w    = tid >> 6;      // wave 0..3 -> units 16w..16w+15
    const int l15  = lane & 15;
    const int lg   = lane >> 4;     // 0..3: k-block for MFMA frags AND my gate type
    const int b    = blockIdx.x;
    const int u    = 16 * w + l15;  // this lane's hidden unit

    // ---------------- W^T B-fragments in registers (once) ----------------
    // B-frag slot (lg,j) of tile ni holds W[16w + 64*ni + l15, kt*32 + lg*8 + j].
    short8 W0[4][2];   // Whh0 (k = h0)
    short8 W1[4][4];   // kt0/1 = Wih1 (k = h0), kt2/3 = Whh1 (k = h1)
    #pragma unroll
    for (int ni = 0; ni < 4; ++ni) {
        const int g = 64 * ni + u;   // gate row: type ni, unit u
        #pragma unroll
        for (int kt = 0; kt < 2; ++kt)
            #pragma unroll
            for (int j = 0; j < 8; ++j) {
                W0[ni][kt][j]     = (short)f2bf(whh0[g * HID + kt * 32 + lg * 8 + j]);
                W1[ni][kt][j]     = (short)f2bf(wih1[g * HID + kt * 32 + lg * 8 + j]);
                W1[ni][2 + kt][j] = (short)f2bf(whh1[g * HID + kt * 32 + lg * 8 + j]);
            }
    }
    // ---- per-lane activation constants (gate-type = lg) ----
    const int   gmy   = 64 * lg + u;                 // my gate row
    const bool  isT   = (lg == 2);                   // gate 'g' is tanh
    const float mselN = isT ? -2.0f : -1.0f;         // exp argument scale
    const float aselN = isT ?  2.0f :  1.0f;         // result remap a*r0+c
    const float cselN = isT ? -1.0f :  0.0f;
    const float bm0   = (bih0[gmy] + bhh0[gmy]) * mselN;  // bias pre-scaled
    const float bm1   = (bih1[gmy] + bhh1[gmy]) * mselN;
    const float wx0 = wih0[gmy * 4 + 0], wx1 = wih0[gmy * 4 + 1];
    const float wx2 = wih0[gmy * 4 + 2], wx3 = wih0[gmy * 4 + 3];
    const float e0 = (lg == 0) ? 1.f : 0.f, e1 = (lg == 1) ? 1.f : 0.f;
    const float e2 = (lg == 2) ? 1.f : 0.f, e3 = (lg == 3) ? 1.f : 0.f;
    const f32x4 Z = {0.f, 0.f, 0.f, 0.f};            // loop-invariant MFMA C-input

    // ---------------- stage x[b] to LDS as f32 (coalesced, once) ----------------
    const float4* __restrict__ xb4 = (const float4*)(x + (size_t)b * (T_STEPS * 4));
    float4* s_xf4 = (float4*)s_xf;
    for (int i2 = tid; i2 < T_STEPS; i2 += 256) s_xf4[i2] = xb4[i2];
    if (tid < HID) {
        s_h0[0][tid] = 0; s_h0[1][tid] = 0;
        s_h1[0][tid] = 0; s_h1[1][tid] = 0;
    }
    __syncthreads();

    float c0s = 0.f, c1s = 0.f, h0s = 0.f, h1s = 0.f;
    float* __restrict__ op = out + (size_t)b * T_STEPS * HID + u;

    // L0 step: gates0 = Whh0*h0(prev) + Wih0*x(t) + b  -> h0(t)
    auto do_L0 = [&](int t, int p, const short8& Ha, const short8& Hb) {
        f32x4 a0 = __builtin_amdgcn_mfma_f32_16x16x32_bf16(Ha, W0[0][0], Z, 0, 0, 0);
        f32x4 a1 = __builtin_amdgcn_mfma_f32_16x16x32_bf16(Ha, W0[1][0], Z, 0, 0, 0);
        f32x4 a2 = __builtin_amdgcn_mfma_f32_16x16x32_bf16(Ha, W0[2][0], Z, 0, 0, 0);
        f32x4 a3 = __builtin_amdgcn_mfma_f32_16x16x32_bf16(Ha, W0[3][0], Z, 0, 0, 0);
        a0 = __builtin_amdgcn_mfma_f32_16x16x32_bf16(Hb, W0[0][1], a0, 0, 0, 0);
        a1 = __builtin_amdgcn_mfma_f32_16x16x32_bf16(Hb, W0[1][1], a1, 0, 0, 0);
        a2 = __builtin_amdgcn_mfma_f32_16x16x32_bf16(Hb, W0[2][1], a2, 0, 0, 0);
        a3 = __builtin_amdgcn_mfma_f32_16x16x32_bf16(Hb, W0[3][1], a3, 0, 0, 0);
        // select MY gate's pre-activation (onehot: 1 mul + 3 fma)
        float s = a0[0] * e0;
        s = fmaf(a1[0], e1, s);
        s = fmaf(a2[0], e2, s);
        s = fmaf(a3[0], e3, s);
        const float4 xt = *(const float4*)&s_xf[4 * t];   // uniform broadcast
        s = fmaf(wx0, xt.x, s);
        s = fmaf(wx1, xt.y, s);
        s = fmaf(wx2, xt.z, s);
        s = fmaf(wx3, xt.w, s);
        // unified sigma-form activation (2 trans)
        float ex = __expf(fmaf(s, mselN, bm0));
        float r  = fmaf(aselN, __builtin_amdgcn_rcpf(1.0f + ex), cselN);
        // gather i,f,g,o onto lg0 (DS pipe)
        float rf = __shfl_xor(r, 16);
        float rg = __shfl_xor(r, 32);
        float ro = __shfl_xor(rf, 32);
        // valid on lg0 only: r=i, rf=f, rg=g, ro=o
        c0s = fmaf(rf, c0s, r * rg);
        h0s = ro * tanh_fast(c0s);
        if (lg == 0) s_h0[p][u] = f2bf(h0s);
    };

    // L1 step: gates1 = Wih1*h0(t) + Whh1*h1(prev) + b  -> h1(t), out1
    auto do_L1 = [&](int t, int p, int q, const short8& Ha, const short8& Hb) {
        const short8 Ga = *(const short8*)&s_h1[q][lg * 8];
        const short8 Gb = *(const short8*)&s_h1[q][32 + lg * 8];
        f32x4 d0 = __builtin_amdgcn_mfma_f32_16x16x32_bf16(Ha, W1[0][0], Z, 0, 0, 0);
        f32x4 d1 = __builtin_amdgcn_mfma_f32_16x16x32_bf16(Ha, W1[1][0], Z, 0, 0, 0);
        f32x4 d2 = __builtin_amdgcn_mfma_f32_16x16x32_bf16(Ha, W1[2][0], Z, 0, 0, 0);
        f32x4 d3 = __builtin_amdgcn_mfma_f32_16x16x32_bf16(Ha, W1[3][0], Z, 0, 0, 0);
        d0 = __builtin_amdgcn_mfma_f32_16x16x32_bf16(Hb, W1[0][1], d0, 0, 0, 0);
        d1 = __builtin_amdgcn_mfma_f32_16x16x32_bf16(Hb, W1[1][1], d1, 0, 0, 0);
        d2 = __builtin_amdgcn_mfma_f32_16x16x32_bf16(Hb, W1[2][1], d2, 0, 0, 0);
        d3 = __builtin_amdgcn_mfma_f32_16x16x32_bf16(Hb, W1[3][1], d3, 0, 0, 0);
        d0 = __builtin_amdgcn_mfma_f32_16x16x32_bf16(Ga, W1[0][2], d0, 0, 0, 0);
        d1 = __builtin_amdgcn_mfma_f32_16x16x32_bf16(Ga, W1[1][2], d1, 0, 0, 0);
        d2 = __builtin_amdgcn_mfma_f32_16x16x32_bf16(Ga, W1[2][2], d2, 0, 0, 0);
        d3 = __builtin_amdgcn_mfma_f32_16x16x32_bf16(Ga, W1[3][2], d3, 0, 0, 0);
        d0 = __builtin_amdgcn_mfma_f32_16x16x32_bf16(Gb, W1[0][3], d0, 0, 0, 0);
        d1 = __builtin_amdgcn_mfma_f32_16x16x32_bf16(Gb, W1[1][3], d1, 0, 0, 0);
        d2 = __builtin_amdgcn_mfma_f32_16x16x32_bf16(Gb, W1[2][3], d2, 0, 0, 0);
        d3 = __builtin_amdgcn_mfma_f32_16x16x32_bf16(Gb, W1[3][3], d3, 0, 0, 0);
        float s = d0[0] * e0;
        s = fmaf(d1[0], e1, s);
        s = fmaf(d2[0], e2, s);
        s = fmaf(d3[0], e3, s);
        float ex = __expf(fmaf(s, mselN, bm1));
        float r  = fmaf(aselN, __builtin_amdgcn_rcpf(1.0f + ex), cselN);
        float rf = __shfl_xor(r, 16);
        float rg = __shfl_xor(r, 32);
        float ro = __shfl_xor(rf, 32);
        c1s = fmaf(rf, c1s, r * rg);
        h1s = ro * tanh_fast(c1s);
        if (lg == 0) {
            s_h1[p][u] = f2bf(h1s);
            op[(size_t)t * HID] = h1s;   // stays in flight across raw barrier
        }
    };

    #define BAR() do { asm volatile("s_waitcnt lgkmcnt(0)" ::: "memory"); \
                       __builtin_amdgcn_s_barrier(); } while (0)

    // ---- i = 0: L0 only ----
    {
        const short8 Ha = *(const short8*)&s_h0[1][lg * 8];
        const short8 Hb = *(const short8*)&s_h0[1][32 + lg * 8];
        do_L0(0, 0, Ha, Hb);
        BAR();
    }
    // ---- main: layer-fused, one barrier per step ----
    for (int i = 1; i < T_STEPS; ++i) {
        const int p = i & 1, q = p ^ 1;
        const short8 Ha = *(const short8*)&s_h0[q][lg * 8];        // h0(i-1)
        const short8 Hb = *(const short8*)&s_h0[q][32 + lg * 8];
        do_L0(i, p, Ha, Hb);          // h0(i)   <- h0(i-1), x(i)
        do_L1(i - 1, p, q, Ha, Hb);   // h1(i-1) <- h0(i-1), h1(i-2)
        BAR();
    }
    // ---- i = T: L1 only ----
    {
        const int p = T_STEPS & 1, q = p ^ 1;
        const short8 Ha = *(const short8*)&s_h0[q][lg * 8];        // h0(T-1)
        const short8 Hb = *(const short8*)&s_h0[q][32 + lg * 8];
        do_L1(T_STEPS - 1, p, q, Ha, Hb);
    }
    #undef BAR

    // ---------------- final states: h_n [2,B,H], c_n [2,B,H] ----------------
    if (lg == 0) {
        const size_t BTH = (size_t)B * T_STEPS * HID;
        const size_t BH  = (size_t)B * HID;
        out[BTH + (size_t)b * HID + u]           = h0s;   // h_n layer0
        out[BTH + BH + (size_t)b * HID + u]      = h1s;   // h_n layer1
        out[BTH + 2 * BH + (size_t)b * HID + u]  = c0s;   // c_n layer0
        out[BTH + 3 * BH + (size_t)b * HID + u]  = c1s;   // c_n layer1
    }
}

extern "C" void kernel_launch(void* const* d_in, const int* in_sizes, int n_in,
                              void* d_out, int out_size, void* d_ws, size_t ws_size,
                              hipStream_t stream) {
    const float* x    = (const float*)d_in[0];
    const float* wih0 = (const float*)d_in[1];
    const float* whh0 = (const float*)d_in[2];
    const float* bih0 = (const float*)d_in[3];
    const float* bhh0 = (const float*)d_in[4];
    const float* wih1 = (const float*)d_in[5];
    const float* whh1 = (const float*)d_in[6];
    const float* bih1 = (const float*)d_in[7];
    const float* bhh1 = (const float*)d_in[8];
    float* out = (float*)d_out;

    const int B = in_sizes[0] / (T_STEPS * 4);   // 512

    lstm2_dist<<<dim3(B), dim3(256), 0, stream>>>(
        x, wih0, whh0, bih0, bhh0, wih1, whh1, bih1, bhh1, out, B);
}

// Round 7
// 993.828 us; speedup vs baseline: 4.6491x; 1.4172x over previous
//
#include <hip/hip_runtime.h>

#define T_STEPS 2048
#define HID 64

typedef __attribute__((ext_vector_type(8))) short short8;
typedef __attribute__((ext_vector_type(4))) float f32x4;

static __device__ __forceinline__ unsigned short f2bf(float f) {
    unsigned int uu = __float_as_uint(f);
    uu = uu + 0x7fffu + ((uu >> 16) & 1u);   // RNE; inputs finite
    return (unsigned short)(uu >> 16);
}
static __device__ __forceinline__ float sigmoid_f(float x) {
    float e = __expf(-x);                            // saturates correctly
    return __builtin_amdgcn_rcpf(1.0f + e);
}
static __device__ __forceinline__ float tanh_fast(float x) {
    float ex = __expf(-2.0f * x);
    return fmaf(2.0f, __builtin_amdgcn_rcpf(1.0f + ex), -1.0f);
}

// TWO batch elements per block (256 blocks -> 1 block/CU via 64KB LDS), 4 waves.
// Swapped MFMA, batches in the M dimension: A row 0 = batch0's h, A row 4 =
// batch1's h (other A rows garbage -- C rows are independent). C row = 4*lg+reg
// (m89) => lg0 lanes hold batch0, lg1 lanes hold batch1, both at acc[0].
// Lane (lg,l15) of wave w owns unit u=16w+l15: gate-type ni lives in acc_ni[0]
// -> all 4 gates per unit per batch on ONE lane, zero shuffles, static indices.
// Bias is pre-loaded into the MFMA C-init vector (loop-invariant).
// Layer-fused skew (L0(i) + L1(i-1), shared h0(i-1) A-frags), ONE raw
// s_barrier per step (lgkmcnt-only wait; out1 stores stay in flight).
__global__ void __launch_bounds__(256, 1) __attribute__((amdgpu_waves_per_eu(1, 1)))
lstm2_b2(const float* __restrict__ x,
         const float* __restrict__ wih0, const float* __restrict__ whh0,
         const float* __restrict__ bih0, const float* __restrict__ bhh0,
         const float* __restrict__ wih1, const float* __restrict__ whh1,
         const float* __restrict__ bih1, const float* __restrict__ bhh1,
         float* __restrict__ out, int B)
{
    __shared__ __align__(16) float s_xf[2 * T_STEPS * 4];     // 64 KB: x[b0],x[b0+1] f32
    __shared__ __align__(16) unsigned short s_h0[2][2][HID];  // [pingpong][batch][unit]
    __shared__ __align__(16) unsigned short s_h1[2][2][HID];

    const int tid  = threadIdx.x;
    const int lane = tid & 63;
    const int w    = tid >> 6;      // wave 0..3 -> units 16w..16w+15
    const int l15  = lane & 15;
    const int lg   = lane >> 4;     // k-block for frags; lg0/lg1 = batch0/batch1 act
    const int b0   = 2 * blockIdx.x;
    const int u    = 16 * w + l15;  // this lane's hidden unit
    const int bx   = lg & 1;        // act/x batch select (valid for lg<2)
    const int rsel = (l15 >> 2) & 1;// A-row h select: l15=0 -> batch0, l15=4 -> batch1

    // ---------------- W^T B-fragments in registers (once) ----------------
    // B-frag slot (lg,j) of tile ni holds W[64*ni + u, kt*32 + lg*8 + j].
    short8 W0[4][2];   // Whh0 (k = h0)
    short8 W1[4][4];   // kt0/1 = Wih1 (k = h0), kt2/3 = Whh1 (k = h1)
    float  wx[4][4];   // Wih0 rows (x-path on VALU, exact f32)
    f32x4  Bias0[4], Bias1[4];   // MFMA C-init: bias of gate col l15 (all 4 rows)
    #pragma unroll
    for (int ni = 0; ni < 4; ++ni) {
        const int g = 64 * ni + u;   // gate row: type ni, unit u
        #pragma unroll
        for (int kt = 0; kt < 2; ++kt)
            #pragma unroll
            for (int j = 0; j < 8; ++j) {
                W0[ni][kt][j]     = (short)f2bf(whh0[g * HID + kt * 32 + lg * 8 + j]);
                W1[ni][kt][j]     = (short)f2bf(wih1[g * HID + kt * 32 + lg * 8 + j]);
                W1[ni][2 + kt][j] = (short)f2bf(whh1[g * HID + kt * 32 + lg * 8 + j]);
            }
        #pragma unroll
        for (int j = 0; j < 4; ++j) wx[ni][j] = wih0[g * 4 + j];
        const float bb0 = bih0[g] + bhh0[g];
        const float bb1 = bih1[g] + bhh1[g];
        Bias0[ni] = (f32x4){bb0, bb0, bb0, bb0};
        Bias1[ni] = (f32x4){bb1, bb1, bb1, bb1};
    }

    // ---------------- stage x[b0], x[b0+1] to LDS f32 (contiguous 64KB) ----------------
    const float4* __restrict__ xb4 = (const float4*)(x + (size_t)b0 * (T_STEPS * 4));
    float4* s_xf4 = (float4*)s_xf;
    for (int i2 = tid; i2 < 2 * T_STEPS; i2 += 256) s_xf4[i2] = xb4[i2];
    ((unsigned short*)s_h0)[tid] = 0;   // 256 entries == 256 threads
    ((unsigned short*)s_h1)[tid] = 0;
    __syncthreads();

    float c0s = 0.f, c1s = 0.f, h0s = 0.f, h1s = 0.f;
    float* __restrict__ op = out + (size_t)(b0 + bx) * T_STEPS * HID + u;

    // L0: gates0 = Whh0*h0(prev) + Wih0*x(t) + b -> h0(t)
    auto do_L0 = [&](int t, int p, const short8& Ha, const short8& Hb) {
        f32x4 a0 = __builtin_amdgcn_mfma_f32_16x16x32_bf16(Ha, W0[0][0], Bias0[0], 0, 0, 0);
        f32x4 a1 = __builtin_amdgcn_mfma_f32_16x16x32_bf16(Ha, W0[1][0], Bias0[1], 0, 0, 0);
        f32x4 a2 = __builtin_amdgcn_mfma_f32_16x16x32_bf16(Ha, W0[2][0], Bias0[2], 0, 0, 0);
        f32x4 a3 = __builtin_amdgcn_mfma_f32_16x16x32_bf16(Ha, W0[3][0], Bias0[3], 0, 0, 0);
        a0 = __builtin_amdgcn_mfma_f32_16x16x32_bf16(Hb, W0[0][1], a0, 0, 0, 0);
        a1 = __builtin_amdgcn_mfma_f32_16x16x32_bf16(Hb, W0[1][1], a1, 0, 0, 0);
        a2 = __builtin_amdgcn_mfma_f32_16x16x32_bf16(Hb, W0[2][1], a2, 0, 0, 0);
        a3 = __builtin_amdgcn_mfma_f32_16x16x32_bf16(Hb, W0[3][1], a3, 0, 0, 0);
        const float4 xt = *(const float4*)&s_xf[(bx * T_STEPS + t) * 4];
        float s0 = a0[0], s1 = a1[0], s2 = a2[0], s3 = a3[0];
        s0 = fmaf(wx[0][0], xt.x, s0); s0 = fmaf(wx[0][1], xt.y, s0);
        s0 = fmaf(wx[0][2], xt.z, s0); s0 = fmaf(wx[0][3], xt.w, s0);
        s1 = fmaf(wx[1][0], xt.x, s1); s1 = fmaf(wx[1][1], xt.y, s1);
        s1 = fmaf(wx[1][2], xt.z, s1); s1 = fmaf(wx[1][3], xt.w, s1);
        s2 = fmaf(wx[2][0], xt.x, s2); s2 = fmaf(wx[2][1], xt.y, s2);
        s2 = fmaf(wx[2][2], xt.z, s2); s2 = fmaf(wx[2][3], xt.w, s2);
        s3 = fmaf(wx[3][0], xt.x, s3); s3 = fmaf(wx[3][1], xt.y, s3);
        s3 = fmaf(wx[3][2], xt.z, s3); s3 = fmaf(wx[3][3], xt.w, s3);
        float i_ = sigmoid_f(s0);
        float f_ = sigmoid_f(s1);
        float g_ = tanh_fast(s2);
        float o_ = sigmoid_f(s3);
        c0s = fmaf(f_, c0s, i_ * g_);
        h0s = o_ * tanh_fast(c0s);
        if (lg < 2) s_h0[p][lg][u] = f2bf(h0s);
    };

    // L1: gates1 = Wih1*h0(t) + Whh1*h1(prev) + b -> h1(t), out1
    auto do_L1 = [&](int t, int p, int q, const short8& Ha, const short8& Hb) {
        const short8 Ga = *(const short8*)&s_h1[q][rsel][8 * lg];
        const short8 Gb = *(const short8*)&s_h1[q][rsel][32 + 8 * lg];
        f32x4 d0 = __builtin_amdgcn_mfma_f32_16x16x32_bf16(Ha, W1[0][0], Bias1[0], 0, 0, 0);
        f32x4 d1 = __builtin_amdgcn_mfma_f32_16x16x32_bf16(Ha, W1[1][0], Bias1[1], 0, 0, 0);
        f32x4 d2 = __builtin_amdgcn_mfma_f32_16x16x32_bf16(Ha, W1[2][0], Bias1[2], 0, 0, 0);
        f32x4 d3 = __builtin_amdgcn_mfma_f32_16x16x32_bf16(Ha, W1[3][0], Bias1[3], 0, 0, 0);
        d0 = __builtin_amdgcn_mfma_f32_16x16x32_bf16(Hb, W1[0][1], d0, 0, 0, 0);
        d1 = __builtin_amdgcn_mfma_f32_16x16x32_bf16(Hb, W1[1][1], d1, 0, 0, 0);
        d2 = __builtin_amdgcn_mfma_f32_16x16x32_bf16(Hb, W1[2][1], d2, 0, 0, 0);
        d3 = __builtin_amdgcn_mfma_f32_16x16x32_bf16(Hb, W1[3][1], d3, 0, 0, 0);
        d0 = __builtin_amdgcn_mfma_f32_16x16x32_bf16(Ga, W1[0][2], d0, 0, 0, 0);
        d1 = __builtin_amdgcn_mfma_f32_16x16x32_bf16(Ga, W1[1][2], d1, 0, 0, 0);
        d2 = __builtin_amdgcn_mfma_f32_16x16x32_bf16(Ga, W1[2][2], d2, 0, 0, 0);
        d3 = __builtin_amdgcn_mfma_f32_16x16x32_bf16(Ga, W1[3][2], d3, 0, 0, 0);
        d0 = __builtin_amdgcn_mfma_f32_16x16x32_bf16(Gb, W1[0][3], d0, 0, 0, 0);
        d1 = __builtin_amdgcn_mfma_f32_16x16x32_bf16(Gb, W1[1][3], d1, 0, 0, 0);
        d2 = __builtin_amdgcn_mfma_f32_16x16x32_bf16(Gb, W1[2][3], d2, 0, 0, 0);
        d3 = __builtin_amdgcn_mfma_f32_16x16x32_bf16(Gb, W1[3][3], d3, 0, 0, 0);
        float i_ = sigmoid_f(d0[0]);
        float f_ = sigmoid_f(d1[0]);
        float g_ = tanh_fast(d2[0]);
        float o_ = sigmoid_f(d3[0]);
        c1s = fmaf(f_, c1s, i_ * g_);
        h1s = o_ * tanh_fast(c1s);
        if (lg < 2) {
            s_h1[p][lg][u] = f2bf(h1s);
            op[(size_t)t * HID] = h1s;   // stays in flight across raw barrier
        }
    };

    #define BAR() do { asm volatile("s_waitcnt lgkmcnt(0)" ::: "memory"); \
                       __builtin_amdgcn_s_barrier(); } while (0)

    // ---- i = 0: L0 only ----
    {
        const short8 Ha = *(const short8*)&s_h0[1][rsel][8 * lg];
        const short8 Hb = *(const short8*)&s_h0[1][rsel][32 + 8 * lg];
        do_L0(0, 0, Ha, Hb);
        BAR();
    }
    // ---- main: layer-fused, one barrier per step ----
    for (int i = 1; i < T_STEPS; ++i) {
        const int p = i & 1, q = p ^ 1;
        const short8 Ha = *(const short8*)&s_h0[q][rsel][8 * lg];        // h0(i-1)
        const short8 Hb = *(const short8*)&s_h0[q][rsel][32 + 8 * lg];
        do_L0(i, p, Ha, Hb);          // h0(i)   <- h0(i-1), x(i)
        do_L1(i - 1, p, q, Ha, Hb);   // h1(i-1) <- h0(i-1), h1(i-2)
        BAR();
    }
    // ---- i = T: L1 only ----
    {
        const int p = T_STEPS & 1, q = p ^ 1;
        const short8 Ha = *(const short8*)&s_h0[q][rsel][8 * lg];        // h0(T-1)
        const short8 Hb = *(const short8*)&s_h0[q][rsel][32 + 8 * lg];
        do_L1(T_STEPS - 1, p, q, Ha, Hb);
    }
    #undef BAR

    // ---------------- final states: h_n [2,B,H], c_n [2,B,H] ----------------
    if (lg < 2) {
        const size_t BTH = (size_t)B * T_STEPS * HID;
        const size_t BH  = (size_t)B * HID;
        const size_t bi  = (size_t)(b0 + bx) * HID + u;
        out[BTH + bi]           = h0s;   // h_n layer0
        out[BTH + BH + bi]      = h1s;   // h_n layer1
        out[BTH + 2 * BH + bi]  = c0s;   // c_n layer0
        out[BTH + 3 * BH + bi]  = c1s;   // c_n layer1
    }
}

extern "C" void kernel_launch(void* const* d_in, const int* in_sizes, int n_in,
                              void* d_out, int out_size, void* d_ws, size_t ws_size,
                              hipStream_t stream) {
    const float* x    = (const float*)d_in[0];
    const float* wih0 = (const float*)d_in[1];
    const float* whh0 = (const float*)d_in[2];
    const float* bih0 = (const float*)d_in[3];
    const float* bhh0 = (const float*)d_in[4];
    const float* wih1 = (const float*)d_in[5];
    const float* whh1 = (const float*)d_in[6];
    const float* bih1 = (const float*)d_in[7];
    const float* bhh1 = (const float*)d_in[8];
    float* out = (float*)d_out;

    const int B = in_sizes[0] / (T_STEPS * 4);   // 512

    lstm2_b2<<<dim3(B / 2), dim3(256), 0, stream>>>(
        x, wih0, whh0, bih0, bhh0, wih1, whh1, bih1, bhh1, out, B);
}

// Round 8
// 804.871 us; speedup vs baseline: 5.7405x; 1.2348x over previous
//
#include <hip/hip_runtime.h>

#define T_STEPS 2048
#define HID 64

typedef __attribute__((ext_vector_type(8))) short short8;
typedef __attribute__((ext_vector_type(4))) float f32x4;

static __device__ __forceinline__ unsigned short f2bf(float f) {
    unsigned int uu = __float_as_uint(f);
    uu = uu + 0x7fffu + ((uu >> 16) & 1u);   // RNE; inputs finite
    return (unsigned short)(uu >> 16);
}
static __device__ __forceinline__ float sigmoid_f(float x) {
    float e = __expf(-x);                            // saturates correctly
    return __builtin_amdgcn_rcpf(1.0f + e);
}
static __device__ __forceinline__ float tanh_fast(float x) {
    float ex = __expf(-2.0f * x);
    return fmaf(2.0f, __builtin_amdgcn_rcpf(1.0f + ex), -1.0f);
}

// TWO batch elements per block (256 blocks, 1 block/CU), 512 threads = 8 waves,
// WAVE-SPECIALIZED: waves 0-3 run the layer0 recurrence (8 MFMA/step), waves
// 4-7 run layer1 (16 MFMA/step). The layer skew (L0(i) || L1(i-1)) makes the
// two groups independent within an iteration; each SIMD hosts one L0-wave +
// one L1-wave, so MFMA issue of one hides the serial activation/c-chain and
// ds_read latency of the other (R7 ran 1 wave/SIMD: 810 cy/step of exposed
// latency).
// Swapped MFMA, batches in M: A row 0 = batch0 h, A row 4 = batch1 h; C row =
// 4*lg+reg => lg0 lanes own batch0, lg1 batch1, gates ni at acc_ni[0] (static).
// One raw s_barrier per step (lgkmcnt-only wait; out1 stores stay in flight).
__global__ void __launch_bounds__(512, 1) __attribute__((amdgpu_waves_per_eu(2, 2)))
lstm2_ws(const float* __restrict__ x,
         const float* __restrict__ wih0, const float* __restrict__ whh0,
         const float* __restrict__ bih0, const float* __restrict__ bhh0,
         const float* __restrict__ wih1, const float* __restrict__ whh1,
         const float* __restrict__ bih1, const float* __restrict__ bhh1,
         float* __restrict__ out, int B)
{
    __shared__ __align__(16) float s_xf[2 * T_STEPS * 4];     // 64 KB: x[b0],x[b0+1] f32
    __shared__ __align__(16) unsigned short s_h0[2][2][HID];  // [pingpong][batch][unit]
    __shared__ __align__(16) unsigned short s_h1[2][2][HID];

    const int tid  = threadIdx.x;
    const int lane = tid & 63;
    const int wv   = tid >> 6;      // wave 0..7
    const int wg   = wv >> 2;       // 0 = L0 group, 1 = L1 group
    const int wl   = wv & 3;        // wave-within-group -> units 16wl..16wl+15
    const int l15  = lane & 15;
    const int lg   = lane >> 4;     // k-block for frags; lg0/lg1 = batch0/batch1
    const int b0   = 2 * blockIdx.x;
    const int u    = 16 * wl + l15; // this lane's hidden unit
    const int bx   = lg & 1;        // act/x batch select (valid for lg<2)
    const int rsel = (l15 >> 2) & 1;// A-row h select (rows 0->b0, 4->b1)

    // ---------------- stage x[b0],x[b0+1] to LDS f32 + init h (common) ----------------
    const float4* __restrict__ xb4 = (const float4*)(x + (size_t)b0 * (T_STEPS * 4));
    float4* s_xf4 = (float4*)s_xf;
    for (int i2 = tid; i2 < 2 * T_STEPS; i2 += 512) s_xf4[i2] = xb4[i2];
    if (tid < 256) {
        ((unsigned short*)s_h0)[tid] = 0;   // both ping-pong buffers, both batches
        ((unsigned short*)s_h1)[tid] = 0;
    }

    const size_t BTH = (size_t)B * T_STEPS * HID;
    const size_t BH  = (size_t)B * HID;
    const size_t bi  = (size_t)(b0 + bx) * HID + u;

    #define BAR() do { asm volatile("s_waitcnt lgkmcnt(0)" ::: "memory"); \
                       __builtin_amdgcn_s_barrier(); } while (0)

    if (wg == 0) {
        // =================== layer0 wave group ===================
        short8 W0[4][2];     // Whh0^T frags
        float  wx[4][4];     // Wih0 rows (x-path on VALU, exact f32)
        f32x4  Bias0[4];
        #pragma unroll
        for (int ni = 0; ni < 4; ++ni) {
            const int g = 64 * ni + u;
            #pragma unroll
            for (int kt = 0; kt < 2; ++kt)
                #pragma unroll
                for (int j = 0; j < 8; ++j)
                    W0[ni][kt][j] = (short)f2bf(whh0[g * HID + kt * 32 + lg * 8 + j]);
            #pragma unroll
            for (int j = 0; j < 4; ++j) wx[ni][j] = wih0[g * 4 + j];
            const float bb = bih0[g] + bhh0[g];
            Bias0[ni] = (f32x4){bb, bb, bb, bb};
        }
        float c0s = 0.f, h0s = 0.f;
        __syncthreads();   // staging visible

        for (int i = 0; i < T_STEPS; ++i) {
            const int p = i & 1, q = p ^ 1;
            const short8 Ha = *(const short8*)&s_h0[q][rsel][8 * lg];        // h0(i-1)
            const short8 Hb = *(const short8*)&s_h0[q][rsel][32 + 8 * lg];
            f32x4 a0 = __builtin_amdgcn_mfma_f32_16x16x32_bf16(Ha, W0[0][0], Bias0[0], 0, 0, 0);
            f32x4 a1 = __builtin_amdgcn_mfma_f32_16x16x32_bf16(Ha, W0[1][0], Bias0[1], 0, 0, 0);
            f32x4 a2 = __builtin_amdgcn_mfma_f32_16x16x32_bf16(Ha, W0[2][0], Bias0[2], 0, 0, 0);
            f32x4 a3 = __builtin_amdgcn_mfma_f32_16x16x32_bf16(Ha, W0[3][0], Bias0[3], 0, 0, 0);
            a0 = __builtin_amdgcn_mfma_f32_16x16x32_bf16(Hb, W0[0][1], a0, 0, 0, 0);
            a1 = __builtin_amdgcn_mfma_f32_16x16x32_bf16(Hb, W0[1][1], a1, 0, 0, 0);
            a2 = __builtin_amdgcn_mfma_f32_16x16x32_bf16(Hb, W0[2][1], a2, 0, 0, 0);
            a3 = __builtin_amdgcn_mfma_f32_16x16x32_bf16(Hb, W0[3][1], a3, 0, 0, 0);
            const float4 xt = *(const float4*)&s_xf[(bx * T_STEPS + i) * 4];
            float s0 = a0[0], s1 = a1[0], s2 = a2[0], s3 = a3[0];
            s0 = fmaf(wx[0][0], xt.x, s0); s0 = fmaf(wx[0][1], xt.y, s0);
            s0 = fmaf(wx[0][2], xt.z, s0); s0 = fmaf(wx[0][3], xt.w, s0);
            s1 = fmaf(wx[1][0], xt.x, s1); s1 = fmaf(wx[1][1], xt.y, s1);
            s1 = fmaf(wx[1][2], xt.z, s1); s1 = fmaf(wx[1][3], xt.w, s1);
            s2 = fmaf(wx[2][0], xt.x, s2); s2 = fmaf(wx[2][1], xt.y, s2);
            s2 = fmaf(wx[2][2], xt.z, s2); s2 = fmaf(wx[2][3], xt.w, s2);
            s3 = fmaf(wx[3][0], xt.x, s3); s3 = fmaf(wx[3][1], xt.y, s3);
            s3 = fmaf(wx[3][2], xt.z, s3); s3 = fmaf(wx[3][3], xt.w, s3);
            float i_ = sigmoid_f(s0);
            float f_ = sigmoid_f(s1);
            float g_ = tanh_fast(s2);
            float o_ = sigmoid_f(s3);
            c0s = fmaf(f_, c0s, i_ * g_);
            h0s = o_ * tanh_fast(c0s);
            if (lg < 2) s_h0[p][lg][u] = f2bf(h0s);
            BAR();
        }
        if (lg < 2) {
            out[BTH + bi]          = h0s;   // h_n layer0
            out[BTH + 2 * BH + bi] = c0s;   // c_n layer0
        }
    } else {
        // =================== layer1 wave group ===================
        short8 W1[4][4];   // kt0/1 = Wih1^T (k = h0), kt2/3 = Whh1^T (k = h1)
        f32x4  Bias1[4];
        #pragma unroll
        for (int ni = 0; ni < 4; ++ni) {
            const int g = 64 * ni + u;
            #pragma unroll
            for (int kt = 0; kt < 2; ++kt)
                #pragma unroll
                for (int j = 0; j < 8; ++j) {
                    W1[ni][kt][j]     = (short)f2bf(wih1[g * HID + kt * 32 + lg * 8 + j]);
                    W1[ni][2 + kt][j] = (short)f2bf(whh1[g * HID + kt * 32 + lg * 8 + j]);
                }
            const float bb = bih1[g] + bhh1[g];
            Bias1[ni] = (f32x4){bb, bb, bb, bb};
        }
        float c1s = 0.f, h1s = 0.f;
        float* __restrict__ op = out + (size_t)(b0 + bx) * T_STEPS * HID + u;
        __syncthreads();   // staging visible
        BAR();             // matches L0 group's i=0 barrier (L1 idle at i=0)

        for (int i = 1; i <= T_STEPS; ++i) {
            // compute h1(i-1) from h0(i-1), h1(i-2)
            const int p = i & 1, q = p ^ 1;
            const short8 Ha = *(const short8*)&s_h0[q][rsel][8 * lg];        // h0(i-1)
            const short8 Hb = *(const short8*)&s_h0[q][rsel][32 + 8 * lg];
            const short8 Ga = *(const short8*)&s_h1[q][rsel][8 * lg];        // h1(i-2)
            const short8 Gb = *(const short8*)&s_h1[q][rsel][32 + 8 * lg];
            f32x4 d0 = __builtin_amdgcn_mfma_f32_16x16x32_bf16(Ha, W1[0][0], Bias1[0], 0, 0, 0);
            f32x4 d1 = __builtin_amdgcn_mfma_f32_16x16x32_bf16(Ha, W1[1][0], Bias1[1], 0, 0, 0);
            f32x4 d2 = __builtin_amdgcn_mfma_f32_16x16x32_bf16(Ha, W1[2][0], Bias1[2], 0, 0, 0);
            f32x4 d3 = __builtin_amdgcn_mfma_f32_16x16x32_bf16(Ha, W1[3][0], Bias1[3], 0, 0, 0);
            d0 = __builtin_amdgcn_mfma_f32_16x16x32_bf16(Hb, W1[0][1], d0, 0, 0, 0);
            d1 = __builtin_amdgcn_mfma_f32_16x16x32_bf16(Hb, W1[1][1], d1, 0, 0, 0);
            d2 = __builtin_amdgcn_mfma_f32_16x16x32_bf16(Hb, W1[2][1], d2, 0, 0, 0);
            d3 = __builtin_amdgcn_mfma_f32_16x16x32_bf16(Hb, W1[3][1], d3, 0, 0, 0);
            d0 = __builtin_amdgcn_mfma_f32_16x16x32_bf16(Ga, W1[0][2], d0, 0, 0, 0);
            d1 = __builtin_amdgcn_mfma_f32_16x16x32_bf16(Ga, W1[1][2], d1, 0, 0, 0);
            d2 = __builtin_amdgcn_mfma_f32_16x16x32_bf16(Ga, W1[2][2], d2, 0, 0, 0);
            d3 = __builtin_amdgcn_mfma_f32_16x16x32_bf16(Ga, W1[3][2], d3, 0, 0, 0);
            d0 = __builtin_amdgcn_mfma_f32_16x16x32_bf16(Gb, W1[0][3], d0, 0, 0, 0);
            d1 = __builtin_amdgcn_mfma_f32_16x16x32_bf16(Gb, W1[1][3], d1, 0, 0, 0);
            d2 = __builtin_amdgcn_mfma_f32_16x16x32_bf16(Gb, W1[2][3], d2, 0, 0, 0);
            d3 = __builtin_amdgcn_mfma_f32_16x16x32_bf16(Gb, W1[3][3], d3, 0, 0, 0);
            float i_ = sigmoid_f(d0[0]);
            float f_ = sigmoid_f(d1[0]);
            float g_ = tanh_fast(d2[0]);
            float o_ = sigmoid_f(d3[0]);
            c1s = fmaf(f_, c1s, i_ * g_);
            h1s = o_ * tanh_fast(c1s);
            if (lg < 2) {
                s_h1[p][lg][u] = f2bf(h1s);
                op[(size_t)(i - 1) * HID] = h1s;   // out1[b,t]; in flight across BAR
            }
            if (i < T_STEPS) BAR();   // last iteration needs no barrier
        }
        if (lg < 2) {
            out[BTH + BH + bi]     = h1s;   // h_n layer1
            out[BTH + 3 * BH + bi] = c1s;   // c_n layer1
        }
    }
    #undef BAR
}

extern "C" void kernel_launch(void* const* d_in, const int* in_sizes, int n_in,
                              void* d_out, int out_size, void* d_ws, size_t ws_size,
                              hipStream_t stream) {
    const float* x    = (const float*)d_in[0];
    const float* wih0 = (const float*)d_in[1];
    const float* whh0 = (const float*)d_in[2];
    const float* bih0 = (const float*)d_in[3];
    const float* bhh0 = (const float*)d_in[4];
    const float* wih1 = (const float*)d_in[5];
    const float* whh1 = (const float*)d_in[6];
    const float* bih1 = (const float*)d_in[7];
    const float* bhh1 = (const float*)d_in[8];
    float* out = (float*)d_out;

    const int B = in_sizes[0] / (T_STEPS * 4);   // 512

    lstm2_ws<<<dim3(B / 2), dim3(512), 0, stream>>>(
        x, wih0, whh0, bih0, bhh0, wih1, whh1, bih1, bhh1, out, B);
}

// Round 9
// 719.826 us; speedup vs baseline: 6.4187x; 1.1181x over previous
//
#include <hip/hip_runtime.h>

#define T_STEPS 2048
#define HID 64

typedef __attribute__((ext_vector_type(8))) short short8;
typedef __attribute__((ext_vector_type(4))) float f32x4;

static __device__ __forceinline__ unsigned short f2bf(float f) {
    unsigned int uu = __float_as_uint(f);
    uu = uu + 0x7fffu + ((uu >> 16) & 1u);   // RNE; inputs finite
    return (unsigned short)(uu >> 16);
}
static __device__ __forceinline__ float exp2_f(float x) {
#if __has_builtin(__builtin_amdgcn_exp2f)
    return __builtin_amdgcn_exp2f(x);
#else
    return exp2f(x);
#endif
}
// weights pre-scaled by -log2e (sigma) / -2log2e (tanh): act = rcp(1+2^s)
static __device__ __forceinline__ float sig2(float s) {          // sigmoid(orig)
    return __builtin_amdgcn_rcpf(1.0f + exp2_f(s));
}
static __device__ __forceinline__ float tanh2(float s) {         // tanh(orig)
    return fmaf(2.0f, __builtin_amdgcn_rcpf(1.0f + exp2_f(s)), -1.0f);
}
#define NLOG2E 1.4426950408889634f

// TWO batch elements per block (256 blocks, 1 block/CU), 512 threads = 8 waves,
// wave-specialized: waves 0-3 = layer0 recurrence, waves 4-7 = layer1 (skewed
// by one step). Swapped MFMA, batches in M rows 0/4 -> lg0/lg1 lanes own
// batch0/batch1 gates at acc[0] (static index, no shuffles).
// R9 changes vs R8: (1) 2x-unrolled main loops with STATIC ping-pong parity ->
// all h LDS addresses fold to base+immediate (h arrays declared first, <64KB
// offsets); (2) activation scale folded into weights (exp2 form, no mul);
// (3) MFMA dep chains split into independent halves + scalar add (latency
// 4L->2L on L1); (4) s_setprio(1) around MFMA clusters (wave role-split
// regime). One raw s_barrier per step, lgkmcnt-only wait.
__global__ void __launch_bounds__(512, 1) __attribute__((amdgpu_waves_per_eu(2, 2)))
lstm2_ws2(const float* __restrict__ x,
          const float* __restrict__ wih0, const float* __restrict__ whh0,
          const float* __restrict__ bih0, const float* __restrict__ bhh0,
          const float* __restrict__ wih1, const float* __restrict__ whh1,
          const float* __restrict__ bih1, const float* __restrict__ bhh1,
          float* __restrict__ out, int B)
{
    // h arrays FIRST: low LDS offsets -> ds_read offset: immediates
    __shared__ __align__(16) unsigned short s_h0[2][2][HID];  // [pingpong][batch][unit]
    __shared__ __align__(16) unsigned short s_h1[2][2][HID];
    __shared__ __align__(16) float s_xf[2 * T_STEPS * 4];     // 64 KB: x[b0],x[b0+1] f32

    const int tid  = threadIdx.x;
    const int lane = tid & 63;
    const int wv   = tid >> 6;      // wave 0..7
    const int wg   = wv >> 2;       // 0 = L0 group, 1 = L1 group
    const int wl   = wv & 3;        // wave-within-group -> units 16wl..16wl+15
    const int l15  = lane & 15;
    const int lg   = lane >> 4;     // k-block for frags; lg0/lg1 = batch0/batch1
    const int b0   = 2 * blockIdx.x;
    const int u    = 16 * wl + l15; // this lane's hidden unit
    const int bx   = lg & 1;        // act/x batch select (valid for lg<2)
    const int rsel = (l15 >> 2) & 1;// A-row h select (row 0 -> b0, row 4 -> b1)

    // per-gate-type activation scale (i,f,g,o) folded into weights/bias
    const float SCL[4] = {-NLOG2E, -NLOG2E, -2.0f * NLOG2E, -NLOG2E};

    // ---------------- stage x + init h (all waves) ----------------
    const float4* __restrict__ xb4 = (const float4*)(x + (size_t)b0 * (T_STEPS * 4));
    float4* s_xf4 = (float4*)s_xf;
    for (int i2 = tid; i2 < 2 * T_STEPS; i2 += 512) s_xf4[i2] = xb4[i2];
    if (tid < 256) {
        ((unsigned short*)s_h0)[tid] = 0;
        ((unsigned short*)s_h1)[tid] = 0;
    }

    const size_t BTH = (size_t)B * T_STEPS * HID;
    const size_t BH  = (size_t)B * HID;
    const size_t bi  = (size_t)(b0 + bx) * HID + u;
    const f32x4 Z = {0.f, 0.f, 0.f, 0.f};

    #define BAR() do { asm volatile("s_waitcnt lgkmcnt(0)" ::: "memory"); \
                       __builtin_amdgcn_s_barrier(); } while (0)

    if (wg == 0) {
        // =================== layer0 wave group ===================
        short8 W0[4][2];     // Whh0^T frags (pre-scaled)
        float  wx[4][4];     // Wih0 rows (pre-scaled, f32 on VALU)
        f32x4  Bias0[4];
        #pragma unroll
        for (int ni = 0; ni < 4; ++ni) {
            const int g = 64 * ni + u;
            const float sc = SCL[ni];
            #pragma unroll
            for (int kt = 0; kt < 2; ++kt)
                #pragma unroll
                for (int j = 0; j < 8; ++j)
                    W0[ni][kt][j] = (short)f2bf(whh0[g * HID + kt * 32 + lg * 8 + j] * sc);
            #pragma unroll
            for (int j = 0; j < 4; ++j) wx[ni][j] = wih0[g * 4 + j] * sc;
            const float bb = (bih0[g] + bhh0[g]) * sc;
            Bias0[ni] = (f32x4){bb, bb, bb, bb};
        }
        float c0s = 0.f, h0s = 0.f;
        const float* xcur = &s_xf[(size_t)bx * T_STEPS * 4];
        __syncthreads();   // staging visible

        // body: one L0 timestep with compile-time parity P
        auto l0_body = [&](int P) {
            const int Q = P ^ 1;
            const short8 Ha = *(const short8*)&s_h0[Q][rsel][8 * lg];   // h0(t-1)
            const short8 Hb = *(const short8*)&s_h0[Q][rsel][32 + 8 * lg];
            const float4 xt = *(const float4*)xcur;  xcur += 4;
            __builtin_amdgcn_s_setprio(1);
            f32x4 aA0 = __builtin_amdgcn_mfma_f32_16x16x32_bf16(Ha, W0[0][0], Bias0[0], 0, 0, 0);
            f32x4 aA1 = __builtin_amdgcn_mfma_f32_16x16x32_bf16(Ha, W0[1][0], Bias0[1], 0, 0, 0);
            f32x4 aA2 = __builtin_amdgcn_mfma_f32_16x16x32_bf16(Ha, W0[2][0], Bias0[2], 0, 0, 0);
            f32x4 aA3 = __builtin_amdgcn_mfma_f32_16x16x32_bf16(Ha, W0[3][0], Bias0[3], 0, 0, 0);
            f32x4 aB0 = __builtin_amdgcn_mfma_f32_16x16x32_bf16(Hb, W0[0][1], Z, 0, 0, 0);
            f32x4 aB1 = __builtin_amdgcn_mfma_f32_16x16x32_bf16(Hb, W0[1][1], Z, 0, 0, 0);
            f32x4 aB2 = __builtin_amdgcn_mfma_f32_16x16x32_bf16(Hb, W0[2][1], Z, 0, 0, 0);
            f32x4 aB3 = __builtin_amdgcn_mfma_f32_16x16x32_bf16(Hb, W0[3][1], Z, 0, 0, 0);
            __builtin_amdgcn_s_setprio(0);
            float s0 = aA0[0] + aB0[0];
            float s1 = aA1[0] + aB1[0];
            float s2 = aA2[0] + aB2[0];
            float s3 = aA3[0] + aB3[0];
            s0 = fmaf(wx[0][0], xt.x, s0); s0 = fmaf(wx[0][1], xt.y, s0);
            s0 = fmaf(wx[0][2], xt.z, s0); s0 = fmaf(wx[0][3], xt.w, s0);
            s1 = fmaf(wx[1][0], xt.x, s1); s1 = fmaf(wx[1][1], xt.y, s1);
            s1 = fmaf(wx[1][2], xt.z, s1); s1 = fmaf(wx[1][3], xt.w, s1);
            s2 = fmaf(wx[2][0], xt.x, s2); s2 = fmaf(wx[2][1], xt.y, s2);
            s2 = fmaf(wx[2][2], xt.z, s2); s2 = fmaf(wx[2][3], xt.w, s2);
            s3 = fmaf(wx[3][0], xt.x, s3); s3 = fmaf(wx[3][1], xt.y, s3);
            s3 = fmaf(wx[3][2], xt.z, s3); s3 = fmaf(wx[3][3], xt.w, s3);
            float i_ = sig2(s0);
            float f_ = sig2(s1);
            float g_ = tanh2(s2);
            float o_ = sig2(s3);
            c0s = fmaf(f_, c0s, i_ * g_);
            h0s = o_ * tanh2(c0s * (-2.0f * NLOG2E));
            if (lg < 2) s_h0[P][lg][u] = f2bf(h0s);
        };

        for (int it = 0; it < T_STEPS / 2; ++it) {
            l0_body(0); BAR();
            l0_body(1); BAR();
        }
        if (lg < 2) {
            out[BTH + bi]          = h0s;   // h_n layer0
            out[BTH + 2 * BH + bi] = c0s;   // c_n layer0
        }
    } else {
        // =================== layer1 wave group ===================
        short8 W1[4][4];   // kt0/1 = Wih1^T (k=h0), kt2/3 = Whh1^T (k=h1), pre-scaled
        f32x4  Bias1[4];
        #pragma unroll
        for (int ni = 0; ni < 4; ++ni) {
            const int g = 64 * ni + u;
            const float sc = SCL[ni];
            #pragma unroll
            for (int kt = 0; kt < 2; ++kt)
                #pragma unroll
                for (int j = 0; j < 8; ++j) {
                    W1[ni][kt][j]     = (short)f2bf(wih1[g * HID + kt * 32 + lg * 8 + j] * sc);
                    W1[ni][2 + kt][j] = (short)f2bf(whh1[g * HID + kt * 32 + lg * 8 + j] * sc);
                }
            const float bb = (bih1[g] + bhh1[g]) * sc;
            Bias1[ni] = (f32x4){bb, bb, bb, bb};
        }
        float c1s = 0.f, h1s = 0.f;
        float* __restrict__ opp = out + (size_t)(b0 + bx) * T_STEPS * HID + u;
        __syncthreads();   // staging visible
        BAR();             // matches L0's first barrier (L1 idle at slot 0)

        // body: computes h1 for the timestep whose h0 sits in slot Q=P^1
        auto l1_body = [&](int P) {
            const int Q = P ^ 1;
            const short8 Ha = *(const short8*)&s_h0[Q][rsel][8 * lg];   // h0(t)
            const short8 Hb = *(const short8*)&s_h0[Q][rsel][32 + 8 * lg];
            const short8 Ga = *(const short8*)&s_h1[Q][rsel][8 * lg];   // h1(t-1)
            const short8 Gb = *(const short8*)&s_h1[Q][rsel][32 + 8 * lg];
            __builtin_amdgcn_s_setprio(1);
            f32x4 dH0 = __builtin_amdgcn_mfma_f32_16x16x32_bf16(Ha, W1[0][0], Bias1[0], 0, 0, 0);
            f32x4 dH1 = __builtin_amdgcn_mfma_f32_16x16x32_bf16(Ha, W1[1][0], Bias1[1], 0, 0, 0);
            f32x4 dH2 = __builtin_amdgcn_mfma_f32_16x16x32_bf16(Ha, W1[2][0], Bias1[2], 0, 0, 0);
            f32x4 dH3 = __builtin_amdgcn_mfma_f32_16x16x32_bf16(Ha, W1[3][0], Bias1[3], 0, 0, 0);
            f32x4 dG0 = __builtin_amdgcn_mfma_f32_16x16x32_bf16(Ga, W1[0][2], Z, 0, 0, 0);
            f32x4 dG1 = __builtin_amdgcn_mfma_f32_16x16x32_bf16(Ga, W1[1][2], Z, 0, 0, 0);
            f32x4 dG2 = __builtin_amdgcn_mfma_f32_16x16x32_bf16(Ga, W1[2][2], Z, 0, 0, 0);
            f32x4 dG3 = __builtin_amdgcn_mfma_f32_16x16x32_bf16(Ga, W1[3][2], Z, 0, 0, 0);
            dH0 = __builtin_amdgcn_mfma_f32_16x16x32_bf16(Hb, W1[0][1], dH0, 0, 0, 0);
            dH1 = __builtin_amdgcn_mfma_f32_16x16x32_bf16(Hb, W1[1][1], dH1, 0, 0, 0);
            dH2 = __builtin_amdgcn_mfma_f32_16x16x32_bf16(Hb, W1[2][1], dH2, 0, 0, 0);
            dH3 = __builtin_amdgcn_mfma_f32_16x16x32_bf16(Hb, W1[3][1], dH3, 0, 0, 0);
            dG0 = __builtin_amdgcn_mfma_f32_16x16x32_bf16(Gb, W1[0][3], dG0, 0, 0, 0);
            dG1 = __builtin_amdgcn_mfma_f32_16x16x32_bf16(Gb, W1[1][3], dG1, 0, 0, 0);
            dG2 = __builtin_amdgcn_mfma_f32_16x16x32_bf16(Gb, W1[2][3], dG2, 0, 0, 0);
            dG3 = __builtin_amdgcn_mfma_f32_16x16x32_bf16(Gb, W1[3][3], dG3, 0, 0, 0);
            __builtin_amdgcn_s_setprio(0);
            float i_ = sig2(dH0[0] + dG0[0]);
            float f_ = sig2(dH1[0] + dG1[0]);
            float g_ = tanh2(dH2[0] + dG2[0]);
            float o_ = sig2(dH3[0] + dG3[0]);
            c1s = fmaf(f_, c1s, i_ * g_);
            h1s = o_ * tanh2(c1s * (-2.0f * NLOG2E));
            if (lg < 2) {
                s_h1[P][lg][u] = f2bf(h1s);
                *opp = h1s;                  // out1[b,t]; in flight across BAR
            }
            opp += HID;
        };

        for (int it = 0; it < T_STEPS / 2 - 1; ++it) {
            l1_body(1); BAR();    // h1(2it)   <- h0(2it) in slot 0, h1(2it-1) in slot 0
            l1_body(0); BAR();    // h1(2it+1) <- h0(2it+1) in slot 1, h1(2it) in slot 1
        }
        l1_body(1); BAR();        // h1(2046)
        l1_body(0);               // h1(2047), no barrier after
        if (lg < 2) {
            out[BTH + BH + bi]     = h1s;   // h_n layer1
            out[BTH + 3 * BH + bi] = c1s;   // c_n layer1
        }
    }
    #undef BAR
}

extern "C" void kernel_launch(void* const* d_in, const int* in_sizes, int n_in,
                              void* d_out, int out_size, void* d_ws, size_t ws_size,
                              hipStream_t stream) {
    const float* x    = (const float*)d_in[0];
    const float* wih0 = (const float*)d_in[1];
    const float* whh0 = (const float*)d_in[2];
    const float* bih0 = (const float*)d_in[3];
    const float* bhh0 = (const float*)d_in[4];
    const float* wih1 = (const float*)d_in[5];
    const float* whh1 = (const float*)d_in[6];
    const float* bih1 = (const float*)d_in[7];
    const float* bhh1 = (const float*)d_in[8];
    float* out = (float*)d_out;

    const int B = in_sizes[0] / (T_STEPS * 4);   // 512

    lstm2_ws2<<<dim3(B / 2), dim3(512), 0, stream>>>(
        x, wih0, whh0, bih0, bhh0, wih1, whh1, bih1, bhh1, out, B);
}